// Round 1
// baseline (1572.017 us; speedup 1.0000x reference)
//
#include <hip/hip_runtime.h>
#include <hip/hip_bf16.h>
#include <cmath>

// ---- constants for this problem -------------------------------------------
#define Bsz   4
#define Tlen  2048
#define Cdim  2048
#define Hn    16
#define Dh    128          // head dim
#define N_QKV 6144         // 3*C

typedef __bf16 bf16x8 __attribute__((ext_vector_type(8)));
typedef __bf16 bf16x4 __attribute__((ext_vector_type(4)));
typedef float  f32x4  __attribute__((ext_vector_type(4)));

__device__ __forceinline__ f32x4 mfma16(bf16x8 a, bf16x8 b, f32x4 c) {
  return __builtin_amdgcn_mfma_f32_16x16x32_bf16(a, b, c, 0, 0, 0);
}

// ---- 0) RoPE cos/sin table: [T][64] each ----------------------------------
__global__ void rope_table_k(float* __restrict__ cosT, float* __restrict__ sinT) {
  int idx = blockIdx.x * 256 + threadIdx.x;      // 0 .. 2048*64-1
  int t = idx >> 6, i = idx & 63;
  // inv_freq = 10000^(-i/64) = exp(-i * ln(10000)/64)
  float invf = __expf(-(float)i * 0.14391156698f);
  float a = (float)t * invf;
  float s, c;
  sincosf(a, &s, &c);                            // precise version (large args)
  cosT[idx] = c;
  sinT[idx] = s;
}

// ---- 1) QKV GEMM + RoPE epilogue -------------------------------------------
// X [8192][2048] f32, W [2048][6144] f32.
// Writes Q,K (RoPE'd) and V as bf16 in [B][H][T][D] layout.
__global__ __launch_bounds__(256) void qkv_rope_gemm(
    const float* __restrict__ X, const float* __restrict__ W,
    __bf16* __restrict__ Qo, __bf16* __restrict__ Ko, __bf16* __restrict__ Vo,
    const float* __restrict__ cosT, const float* __restrict__ sinT)
{
  __shared__ union SM1 {
    struct { __bf16 A[128][40]; __bf16 B[128][40]; } s;  // B stored [n][k]
    float C[128][129];                                    // epilogue tile
  } sm;

  const int tid  = threadIdx.x;
  const int lane = tid & 63;
  const int wid  = tid >> 6;
  const int g    = lane >> 4, l16 = lane & 15;
  const int wr   = wid >> 1,  wc  = wid & 1;
  const int m0   = blockIdx.y * 128;
  const int n0   = blockIdx.x * 128;

  const int ar = tid >> 1, ac = (tid & 1) * 16;   // A stage: row, col base
  const int br = tid >> 3, bc = (tid & 7) * 16;   // B stage: k-row, n-col base
  const float* Ab = X + (size_t)(m0 + ar) * Cdim + ac;
  const float* Bb = W + (size_t)br * N_QKV + n0 + bc;

  f32x4 acc[4][4] = {};

  for (int k0 = 0; k0 < Cdim; k0 += 32) {
    __syncthreads();
    // stage A tile (128x32) fp32 -> bf16
    #pragma unroll
    for (int u = 0; u < 4; ++u) {
      f32x4 v = *(const f32x4*)(Ab + k0 + u * 4);
      bf16x4 w;
      w[0] = (__bf16)v[0]; w[1] = (__bf16)v[1];
      w[2] = (__bf16)v[2]; w[3] = (__bf16)v[3];
      *(bf16x4*)&sm.s.A[ar][ac + u * 4] = w;
    }
    // stage B tile (32x128) transposed -> [n][k]
    const float* bs = Bb + (size_t)k0 * N_QKV;
    #pragma unroll
    for (int u = 0; u < 4; ++u) {
      f32x4 v = *(const f32x4*)(bs + u * 4);
      sm.s.B[bc + u * 4 + 0][br] = (__bf16)v[0];
      sm.s.B[bc + u * 4 + 1][br] = (__bf16)v[1];
      sm.s.B[bc + u * 4 + 2][br] = (__bf16)v[2];
      sm.s.B[bc + u * 4 + 3][br] = (__bf16)v[3];
    }
    __syncthreads();

    bf16x8 a[4], b[4];
    #pragma unroll
    for (int i = 0; i < 4; ++i) {
      a[i] = *(const bf16x8*)&sm.s.A[wr * 64 + i * 16 + l16][8 * g];
      b[i] = *(const bf16x8*)&sm.s.B[wc * 64 + i * 16 + l16][8 * g];
    }
    #pragma unroll
    for (int mf = 0; mf < 4; ++mf)
      #pragma unroll
      for (int nf = 0; nf < 4; ++nf)
        acc[mf][nf] = mfma16(a[mf], b[nf], acc[mf][nf]);
  }

  // move acc -> LDS f32 tile (need d and d+64 pairing for RoPE)
  __syncthreads();
  #pragma unroll
  for (int mf = 0; mf < 4; ++mf)
    #pragma unroll
    for (int nf = 0; nf < 4; ++nf)
      #pragma unroll
      for (int r = 0; r < 4; ++r)
        sm.C[wr * 64 + mf * 16 + g * 4 + r][wc * 64 + nf * 16 + l16] = acc[mf][nf][r];
  __syncthreads();

  const int sel  = n0 >> 11;          // 0=q 1=k 2=v
  const int h    = (n0 & 2047) >> 7;  // head
  const int row  = tid >> 1;
  const int coff = (tid & 1) * 32;
  const int m    = m0 + row;
  const int b_   = m >> 11, t = m & 2047;
  __bf16* dst = (sel == 0) ? Qo : (sel == 1) ? Ko : Vo;
  __bf16* out = dst + (((size_t)(b_ * Hn + h)) * Tlen + t) * Dh;
  const float* cb = cosT + t * 64 + coff;
  const float* sb = sinT + t * 64 + coff;

  bf16x8 b1, b2;
  #pragma unroll
  for (int i = 0; i < 32; ++i) {
    float v1 = sm.C[row][coff + i];
    float v2 = sm.C[row][coff + i + 64];
    float o1, o2;
    if (sel == 2) { o1 = v1; o2 = v2; }
    else {
      float cs = cb[i], sn = sb[i];
      o1 = v1 * cs - v2 * sn;           // d < 64
      o2 = v2 * cs + v1 * sn;           // d >= 64
    }
    b1[i & 7] = (__bf16)o1;
    b2[i & 7] = (__bf16)o2;
    if ((i & 7) == 7) {
      *(bf16x8*)&out[coff + (i - 7)]      = b1;
      *(bf16x8*)&out[coff + (i - 7) + 64] = b2;
    }
  }
}

// ---- 2) Flash attention (causal) -------------------------------------------
// Q,K,V bf16 [B][H][T][D]; Y written back over Q buffer (same layout).
__global__ __launch_bounds__(256) void attn_fwd(
    const __bf16* Qg, const __bf16* __restrict__ Kg,
    const __bf16* __restrict__ Vg, __bf16* Yg)
{
  __shared__ __bf16 Qs[64][136];
  __shared__ __bf16 Ks[64][136];
  __shared__ __bf16 Vt[128][72];     // V transposed: [d][kv]
  __shared__ __bf16 Ps[4][16][72];   // per-wave P tile

  const int tid  = threadIdx.x;
  const int lane = tid & 63;
  const int wid  = tid >> 6;
  const int g    = lane >> 4, l16 = lane & 15;
  const int q0   = blockIdx.x * 64;
  const size_t bh = ((size_t)blockIdx.z * Hn + blockIdx.y) * Tlen;

  const int sr = tid >> 2, sc = (tid & 3) * 32;

  // stage Q tile once
  {
    const bf16x8* src = (const bf16x8*)(Qg + (bh + q0 + sr) * Dh + sc);
    #pragma unroll
    for (int u = 0; u < 4; ++u) *(bf16x8*)&Qs[sr][sc + u * 8] = src[u];
  }

  float m_r[4] = {-1e30f, -1e30f, -1e30f, -1e30f};
  float l_r[4] = {0.f, 0.f, 0.f, 0.f};
  f32x4 o[8] = {};
  const int qrow_w = wid * 16;

  for (int kv0 = 0; kv0 <= q0; kv0 += 64) {
    __syncthreads();
    // stage K and V^T tiles
    {
      const bf16x8* ksrc = (const bf16x8*)(Kg + (bh + kv0 + sr) * Dh + sc);
      #pragma unroll
      for (int u = 0; u < 4; ++u) *(bf16x8*)&Ks[sr][sc + u * 8] = ksrc[u];
      const bf16x8* vsrc = (const bf16x8*)(Vg + (bh + kv0 + sr) * Dh + sc);
      #pragma unroll
      for (int u = 0; u < 4; ++u) {
        bf16x8 vv = vsrc[u];
        #pragma unroll
        for (int j = 0; j < 8; ++j) Vt[sc + u * 8 + j][sr] = vv[j];
      }
    }
    __syncthreads();

    // S = Q_w @ K^T  (16 x 64)
    f32x4 s[4] = {};
    #pragma unroll
    for (int ks = 0; ks < 4; ++ks) {
      bf16x8 aq = *(const bf16x8*)&Qs[qrow_w + l16][ks * 32 + 8 * g];
      #pragma unroll
      for (int nf = 0; nf < 4; ++nf) {
        bf16x8 bk = *(const bf16x8*)&Ks[nf * 16 + l16][ks * 32 + 8 * g];
        s[nf] = mfma16(aq, bk, s[nf]);
      }
    }

    const float scl = 0.08838834764831845f;  // 1/sqrt(128)
    const bool diag = (kv0 == q0);
    float mx[4];
    #pragma unroll
    for (int r = 0; r < 4; ++r) {
      #pragma unroll
      for (int nf = 0; nf < 4; ++nf) {
        float v = s[nf][r] * scl;
        int qrow = qrow_w + 4 * g + r;
        if (diag && (nf * 16 + l16) > qrow) v = -1e30f;
        s[nf][r] = v;
      }
      mx[r] = fmaxf(fmaxf(s[0][r], s[1][r]), fmaxf(s[2][r], s[3][r]));
    }
    #pragma unroll
    for (int off = 1; off < 16; off <<= 1) {
      #pragma unroll
      for (int r = 0; r < 4; ++r) mx[r] = fmaxf(mx[r], __shfl_xor(mx[r], off, 64));
    }

    float al[4], rs[4];
    #pragma unroll
    for (int r = 0; r < 4; ++r) {
      float mn = fmaxf(m_r[r], mx[r]);
      al[r] = __expf(m_r[r] - mn);
      m_r[r] = mn;
      rs[r] = 0.f;
    }
    #pragma unroll
    for (int nf = 0; nf < 4; ++nf)
      #pragma unroll
      for (int r = 0; r < 4; ++r) {
        float p = __expf(s[nf][r] - m_r[r]);
        s[nf][r] = p;
        rs[r] += p;
      }
    #pragma unroll
    for (int off = 1; off < 16; off <<= 1) {
      #pragma unroll
      for (int r = 0; r < 4; ++r) rs[r] += __shfl_xor(rs[r], off, 64);
    }
    #pragma unroll
    for (int r = 0; r < 4; ++r) l_r[r] = l_r[r] * al[r] + rs[r];
    #pragma unroll
    for (int nf2 = 0; nf2 < 8; ++nf2)
      #pragma unroll
      for (int r = 0; r < 4; ++r) o[nf2][r] *= al[r];

    // P -> per-wave LDS (transpose C-layout -> A-fragment layout)
    #pragma unroll
    for (int nf = 0; nf < 4; ++nf)
      #pragma unroll
      for (int r = 0; r < 4; ++r)
        Ps[wid][4 * g + r][nf * 16 + l16] = (__bf16)s[nf][r];
    __syncthreads();  // safety: order P writes before reads (uniform barrier)

    bf16x8 pa0 = *(const bf16x8*)&Ps[wid][l16][8 * g];
    bf16x8 pa1 = *(const bf16x8*)&Ps[wid][l16][32 + 8 * g];
    #pragma unroll
    for (int nf2 = 0; nf2 < 8; ++nf2) {
      bf16x8 vb0 = *(const bf16x8*)&Vt[nf2 * 16 + l16][8 * g];
      bf16x8 vb1 = *(const bf16x8*)&Vt[nf2 * 16 + l16][32 + 8 * g];
      o[nf2] = mfma16(pa0, vb0, o[nf2]);
      o[nf2] = mfma16(pa1, vb1, o[nf2]);
    }
  }

  // finalize: y = o / l, write over Q buffer
  float inv[4];
  #pragma unroll
  for (int r = 0; r < 4; ++r) inv[r] = 1.0f / l_r[r];
  __bf16* ybase = Yg + (bh + q0 + qrow_w) * Dh;
  #pragma unroll
  for (int nf2 = 0; nf2 < 8; ++nf2)
    #pragma unroll
    for (int r = 0; r < 4; ++r)
      ybase[(size_t)(4 * g + r) * Dh + nf2 * 16 + l16] = (__bf16)(o[nf2][r] * inv[r]);
}

// ---- 3) output GEMM: out = Y @ Wout ----------------------------------------
// Y bf16 in [B][H][T][D] layout (k = h*128 + d), Wout f32 [2048][2048].
__global__ __launch_bounds__(256) void out_gemm(
    const __bf16* __restrict__ Y, const float* __restrict__ W,
    float* __restrict__ O)
{
  __shared__ __bf16 As[128][40];
  __shared__ __bf16 Bs[128][40];   // [n][k]

  const int tid  = threadIdx.x;
  const int lane = tid & 63;
  const int wid  = tid >> 6;
  const int g    = lane >> 4, l16 = lane & 15;
  const int wr   = wid >> 1,  wc  = wid & 1;
  const int m0   = blockIdx.y * 128;
  const int n0   = blockIdx.x * 128;

  const int ar = tid >> 1, ac = (tid & 1) * 16;
  const int br = tid >> 3, bc = (tid & 7) * 16;
  const int m  = m0 + ar, b_ = m >> 11, t = m & 2047;
  const __bf16* Yrow = Y + ((size_t)b_ * Hn) * Tlen * Dh + (size_t)t * Dh;
  const float*  Bb   = W + (size_t)br * Cdim + n0 + bc;

  f32x4 acc[4][4] = {};

  for (int k0 = 0; k0 < Cdim; k0 += 32) {
    __syncthreads();
    {
      int kk = k0 + ac;
      int hh = kk >> 7, d = kk & 127;
      const __bf16* src = Yrow + (size_t)hh * (Tlen * Dh) + d;
      *(bf16x8*)&As[ar][ac]     = *(const bf16x8*)src;
      *(bf16x8*)&As[ar][ac + 8] = *(const bf16x8*)(src + 8);
    }
    const float* bs = Bb + (size_t)k0 * Cdim;
    #pragma unroll
    for (int u = 0; u < 4; ++u) {
      f32x4 v = *(const f32x4*)(bs + u * 4);
      Bs[bc + u * 4 + 0][br] = (__bf16)v[0];
      Bs[bc + u * 4 + 1][br] = (__bf16)v[1];
      Bs[bc + u * 4 + 2][br] = (__bf16)v[2];
      Bs[bc + u * 4 + 3][br] = (__bf16)v[3];
    }
    __syncthreads();

    bf16x8 a[4], b[4];
    #pragma unroll
    for (int i = 0; i < 4; ++i) {
      a[i] = *(const bf16x8*)&As[wr * 64 + i * 16 + l16][8 * g];
      b[i] = *(const bf16x8*)&Bs[wc * 64 + i * 16 + l16][8 * g];
    }
    #pragma unroll
    for (int mf = 0; mf < 4; ++mf)
      #pragma unroll
      for (int nf = 0; nf < 4; ++nf)
        acc[mf][nf] = mfma16(a[mf], b[nf], acc[mf][nf]);
  }

  #pragma unroll
  for (int mf = 0; mf < 4; ++mf)
    #pragma unroll
    for (int nf = 0; nf < 4; ++nf)
      #pragma unroll
      for (int r = 0; r < 4; ++r)
        O[(size_t)(m0 + wr * 64 + mf * 16 + g * 4 + r) * Cdim
          + (n0 + wc * 64 + nf * 16 + l16)] = acc[mf][nf][r];
}

// ---- launch -----------------------------------------------------------------
extern "C" void kernel_launch(void* const* d_in, const int* in_sizes, int n_in,
                              void* d_out, int out_size, void* d_ws, size_t ws_size,
                              hipStream_t stream) {
  const float* x    = (const float*)d_in[0];
  const float* Wqkv = (const float*)d_in[1];
  const float* Wout = (const float*)d_in[2];
  float* out = (float*)d_out;

  // workspace layout
  float* cosT = (float*)d_ws;                       // [2048][64]
  float* sinT = cosT + Tlen * 64;                   // [2048][64]
  __bf16* Qb  = (__bf16*)(sinT + Tlen * 64);        // [B][H][T][D]
  __bf16* Kb  = Qb + (size_t)Bsz * Hn * Tlen * Dh;
  __bf16* Vb  = Kb + (size_t)Bsz * Hn * Tlen * Dh;

  rope_table_k<<<dim3(512), dim3(256), 0, stream>>>(cosT, sinT);
  qkv_rope_gemm<<<dim3(N_QKV / 128, (Bsz * Tlen) / 128), dim3(256), 0, stream>>>(
      x, Wqkv, Qb, Kb, Vb, cosT, sinT);
  attn_fwd<<<dim3(Tlen / 64, Hn, Bsz), dim3(256), 0, stream>>>(Qb, Kb, Vb, Qb);
  out_gemm<<<dim3(Cdim / 128, (Bsz * Tlen) / 128), dim3(256), 0, stream>>>(
      Qb, Wout, out);
}

// Round 2
// 1412.083 us; speedup vs baseline: 1.1133x; 1.1133x over previous
//
#include <hip/hip_runtime.h>
#include <hip/hip_bf16.h>
#include <cmath>

// ---- constants -------------------------------------------------------------
#define Bsz   4
#define Tlen  2048
#define Cdim  2048
#define Hn    16
#define Dh    128
#define N_QKV 6144
#define Mrows 8192          // B*T

typedef __bf16 bf16x8 __attribute__((ext_vector_type(8)));
typedef __bf16 bf16x4 __attribute__((ext_vector_type(4)));
typedef float  f32x4  __attribute__((ext_vector_type(4)));

__device__ __forceinline__ f32x4 mfma16(bf16x8 a, bf16x8 b, f32x4 c) {
  return __builtin_amdgcn_mfma_f32_16x16x32_bf16(a, b, c, 0, 0, 0);
}

// async global->LDS, 16B per lane; lds ptr must be wave-uniform slice base.
__device__ __forceinline__ void gl16(const void* g, void* l) {
  __builtin_amdgcn_global_load_lds(
      (const __attribute__((address_space(1))) void*)g,
      (__attribute__((address_space(3))) void*)l, 16, 0, 0);
}

// ---- 0) RoPE cos/sin table: [T][64] each ----------------------------------
__global__ void rope_table_k(float* __restrict__ cosT, float* __restrict__ sinT) {
  int idx = blockIdx.x * 256 + threadIdx.x;
  int t = idx >> 6, i = idx & 63;
  float invf = __expf(-(float)i * 0.14391156698f);   // 10000^(-i/64)
  float a = (float)t * invf;
  float s, c;
  sincosf(a, &s, &c);
  cosT[idx] = c;
  sinT[idx] = s;
}

// ---- 0b) X fp32 -> bf16 (row-major) ----------------------------------------
__global__ __launch_bounds__(256) void f32_to_bf16_k(
    const float* __restrict__ src, __bf16* __restrict__ dst) {
  size_t i = ((size_t)blockIdx.x * 256 + threadIdx.x) * 8;
  f32x4 a = *(const f32x4*)(src + i);
  f32x4 b = *(const f32x4*)(src + i + 4);
  bf16x8 o;
  o[0] = (__bf16)a[0]; o[1] = (__bf16)a[1]; o[2] = (__bf16)a[2]; o[3] = (__bf16)a[3];
  o[4] = (__bf16)b[0]; o[5] = (__bf16)b[1]; o[6] = (__bf16)b[2]; o[7] = (__bf16)b[3];
  *(bf16x8*)(dst + i) = o;
}

// ---- 0c) W fp32 [K][N] -> bf16 [N][K] (B^T form) ---------------------------
__global__ __launch_bounds__(256) void transpose_to_bf16_k(
    const float* __restrict__ src, __bf16* __restrict__ dst, int K, int N) {
  __shared__ float tile[32][33];
  int n0 = blockIdx.x * 32, k0 = blockIdx.y * 32;
  int tr = threadIdx.x >> 3, tc = (threadIdx.x & 7) * 4;
  f32x4 v = *(const f32x4*)&src[(size_t)(k0 + tr) * N + n0 + tc];
  tile[tr][tc + 0] = v[0]; tile[tr][tc + 1] = v[1];
  tile[tr][tc + 2] = v[2]; tile[tr][tc + 3] = v[3];
  __syncthreads();
  bf16x4 w;
  w[0] = (__bf16)tile[tc + 0][tr];
  w[1] = (__bf16)tile[tc + 1][tr];
  w[2] = (__bf16)tile[tc + 2][tr];
  w[3] = (__bf16)tile[tc + 3][tr];
  *(bf16x4*)&dst[(size_t)(n0 + tr) * K + k0 + tc] = w;
}

// ---- 1) QKV GEMM (m97 structure) + RoPE epilogue ---------------------------
// Xb [8192][2048] bf16, Wt [6144][2048] bf16 (B^T). Q,K RoPE'd; out [B][H][T][D].
__global__ __launch_bounds__(256) void qkv_gemm(
    const __bf16* __restrict__ Xb, const __bf16* __restrict__ Wt,
    __bf16* __restrict__ Qo, __bf16* __restrict__ Ko, __bf16* __restrict__ Vo,
    const float* __restrict__ cosT, const float* __restrict__ sinT)
{
  __shared__ union SM {
    struct { __bf16 A[128][32]; __bf16 B[128][32]; } s;   // linear (gl_lds)
    float C[64][132];                                      // epilogue half-tile
  } sm;

  const int tid = threadIdx.x, lane = tid & 63, wid = tid >> 6;
  const int g = lane >> 4, l16 = lane & 15;
  const int wr = wid >> 1, wc = wid & 1;
  const int m0 = blockIdx.y * 128, n0 = blockIdx.x * 128;

  const __bf16* gA = Xb + (size_t)(m0 + wid * 32 + (lane >> 2)) * Cdim + (lane & 3) * 8;
  const __bf16* gB = Wt + (size_t)(n0 + wid * 32 + (lane >> 2)) * Cdim + (lane & 3) * 8;
  __bf16* lA0 = &sm.s.A[wid * 32][0];
  __bf16* lA1 = &sm.s.A[wid * 32 + 16][0];
  __bf16* lB0 = &sm.s.B[wid * 32][0];
  __bf16* lB1 = &sm.s.B[wid * 32 + 16][0];

  f32x4 acc[4][4] = {};

  for (int k0 = 0; k0 < Cdim; k0 += 32) {
    __syncthreads();
    gl16(gA + k0,              lA0);
    gl16(gA + k0 + 16 * Cdim,  lA1);
    gl16(gB + k0,              lB0);
    gl16(gB + k0 + 16 * Cdim,  lB1);
    __syncthreads();           // compiler drains vmcnt before barrier

    bf16x8 a[4], b[4];
    #pragma unroll
    for (int i = 0; i < 4; ++i) {
      a[i] = *(const bf16x8*)&sm.s.A[wr * 64 + i * 16 + l16][8 * g];
      b[i] = *(const bf16x8*)&sm.s.B[wc * 64 + i * 16 + l16][8 * g];
    }
    #pragma unroll
    for (int mf = 0; mf < 4; ++mf)
      #pragma unroll
      for (int nf = 0; nf < 4; ++nf)
        acc[mf][nf] = mfma16(a[mf], b[nf], acc[mf][nf]);
  }

  // epilogue: two 64-row halves through LDS f32, RoPE, bf16 store
  const int sel = n0 >> 11;           // 0=q 1=k 2=v
  const int h   = (n0 & 2047) >> 7;
  __bf16* dst = (sel == 0) ? Qo : (sel == 1) ? Ko : Vo;
  const int row = tid >> 2, jb = (tid & 3) * 16;

  #pragma unroll
  for (int rh = 0; rh < 2; ++rh) {
    __syncthreads();
    if (wr == rh) {
      #pragma unroll
      for (int mf = 0; mf < 4; ++mf)
        #pragma unroll
        for (int nf = 0; nf < 4; ++nf)
          #pragma unroll
          for (int r = 0; r < 4; ++r)
            sm.C[mf * 16 + g * 4 + r][wc * 64 + nf * 16 + l16] = acc[mf][nf][r];
    }
    __syncthreads();
    int m = m0 + rh * 64 + row;
    int b_ = m >> 11, t = m & 2047;
    __bf16* out = dst + (((size_t)(b_ * Hn + h)) * Tlen + t) * Dh;
    const float* cb = cosT + t * 64 + jb;
    const float* sb = sinT + t * 64 + jb;
    bf16x8 o1[2], o2[2];
    #pragma unroll
    for (int i = 0; i < 16; ++i) {
      float v1 = sm.C[row][jb + i];
      float v2 = sm.C[row][jb + i + 64];
      float r1, r2;
      if (sel == 2) { r1 = v1; r2 = v2; }
      else {
        float cs = cb[i], sn = sb[i];
        r1 = v1 * cs - v2 * sn;
        r2 = v2 * cs + v1 * sn;
      }
      o1[i >> 3][i & 7] = (__bf16)r1;
      o2[i >> 3][i & 7] = (__bf16)r2;
    }
    *(bf16x8*)&out[jb]      = o1[0];
    *(bf16x8*)&out[jb + 8]  = o1[1];
    *(bf16x8*)&out[jb + 64] = o2[0];
    *(bf16x8*)&out[jb + 72] = o2[1];
  }
}

// ---- 2) Flash attention (causal) -------------------------------------------
// Q,K,V bf16 [B][H][T][D]; Y written to [B][T][C] layout buffer.
__global__ __launch_bounds__(256) void attn_fwd(
    const __bf16* __restrict__ Qg, const __bf16* __restrict__ Kg,
    const __bf16* __restrict__ Vg, __bf16* __restrict__ Yg)
{
  __shared__ __bf16 Qs[64][136];
  __shared__ __bf16 Ks[64][136];
  __shared__ __bf16 Vt[128][72];
  __shared__ __bf16 Ps[4][16][72];

  const int tid  = threadIdx.x;
  const int lane = tid & 63;
  const int wid  = tid >> 6;
  const int g    = lane >> 4, l16 = lane & 15;
  const int q0   = blockIdx.x * 64;
  const size_t bh = ((size_t)blockIdx.z * Hn + blockIdx.y) * Tlen;

  const int sr = tid >> 2, sc = (tid & 3) * 32;

  {
    const bf16x8* src = (const bf16x8*)(Qg + (bh + q0 + sr) * Dh + sc);
    #pragma unroll
    for (int u = 0; u < 4; ++u) *(bf16x8*)&Qs[sr][sc + u * 8] = src[u];
  }

  float m_r[4] = {-1e30f, -1e30f, -1e30f, -1e30f};
  float l_r[4] = {0.f, 0.f, 0.f, 0.f};
  f32x4 o[8] = {};
  const int qrow_w = wid * 16;

  for (int kv0 = 0; kv0 <= q0; kv0 += 64) {
    __syncthreads();
    {
      const bf16x8* ksrc = (const bf16x8*)(Kg + (bh + kv0 + sr) * Dh + sc);
      #pragma unroll
      for (int u = 0; u < 4; ++u) *(bf16x8*)&Ks[sr][sc + u * 8] = ksrc[u];
      const bf16x8* vsrc = (const bf16x8*)(Vg + (bh + kv0 + sr) * Dh + sc);
      #pragma unroll
      for (int u = 0; u < 4; ++u) {
        bf16x8 vv = vsrc[u];
        #pragma unroll
        for (int j = 0; j < 8; ++j) Vt[sc + u * 8 + j][sr] = vv[j];
      }
    }
    __syncthreads();

    f32x4 s[4] = {};
    #pragma unroll
    for (int ks = 0; ks < 4; ++ks) {
      bf16x8 aq = *(const bf16x8*)&Qs[qrow_w + l16][ks * 32 + 8 * g];
      #pragma unroll
      for (int nf = 0; nf < 4; ++nf) {
        bf16x8 bk = *(const bf16x8*)&Ks[nf * 16 + l16][ks * 32 + 8 * g];
        s[nf] = mfma16(aq, bk, s[nf]);
      }
    }

    const float scl = 0.08838834764831845f;
    const bool diag = (kv0 == q0);
    float mx[4];
    #pragma unroll
    for (int r = 0; r < 4; ++r) {
      #pragma unroll
      for (int nf = 0; nf < 4; ++nf) {
        float v = s[nf][r] * scl;
        int qrow = qrow_w + 4 * g + r;
        if (diag && (nf * 16 + l16) > qrow) v = -1e30f;
        s[nf][r] = v;
      }
      mx[r] = fmaxf(fmaxf(s[0][r], s[1][r]), fmaxf(s[2][r], s[3][r]));
    }
    #pragma unroll
    for (int off = 1; off < 16; off <<= 1) {
      #pragma unroll
      for (int r = 0; r < 4; ++r) mx[r] = fmaxf(mx[r], __shfl_xor(mx[r], off, 64));
    }

    float al[4], rs[4];
    #pragma unroll
    for (int r = 0; r < 4; ++r) {
      float mn = fmaxf(m_r[r], mx[r]);
      al[r] = __expf(m_r[r] - mn);
      m_r[r] = mn;
      rs[r] = 0.f;
    }
    #pragma unroll
    for (int nf = 0; nf < 4; ++nf)
      #pragma unroll
      for (int r = 0; r < 4; ++r) {
        float p = __expf(s[nf][r] - m_r[r]);
        s[nf][r] = p;
        rs[r] += p;
      }
    #pragma unroll
    for (int off = 1; off < 16; off <<= 1) {
      #pragma unroll
      for (int r = 0; r < 4; ++r) rs[r] += __shfl_xor(rs[r], off, 64);
    }
    #pragma unroll
    for (int r = 0; r < 4; ++r) l_r[r] = l_r[r] * al[r] + rs[r];
    #pragma unroll
    for (int nf2 = 0; nf2 < 8; ++nf2)
      #pragma unroll
      for (int r = 0; r < 4; ++r) o[nf2][r] *= al[r];

    #pragma unroll
    for (int nf = 0; nf < 4; ++nf)
      #pragma unroll
      for (int r = 0; r < 4; ++r)
        Ps[wid][4 * g + r][nf * 16 + l16] = (__bf16)s[nf][r];
    __syncthreads();

    bf16x8 pa0 = *(const bf16x8*)&Ps[wid][l16][8 * g];
    bf16x8 pa1 = *(const bf16x8*)&Ps[wid][l16][32 + 8 * g];
    #pragma unroll
    for (int nf2 = 0; nf2 < 8; ++nf2) {
      bf16x8 vb0 = *(const bf16x8*)&Vt[nf2 * 16 + l16][8 * g];
      bf16x8 vb1 = *(const bf16x8*)&Vt[nf2 * 16 + l16][32 + 8 * g];
      o[nf2] = mfma16(pa0, vb0, o[nf2]);
      o[nf2] = mfma16(pa1, vb1, o[nf2]);
    }
  }

  float inv[4];
  #pragma unroll
  for (int r = 0; r < 4; ++r) inv[r] = 1.0f / l_r[r];
  // Y in [B][T][C] layout: row = b*T + t, col = h*128 + d
  __bf16* ybase = Yg + ((size_t)(blockIdx.z * Tlen + q0 + qrow_w)) * Cdim
                + blockIdx.y * Dh;
  #pragma unroll
  for (int nf2 = 0; nf2 < 8; ++nf2)
    #pragma unroll
    for (int r = 0; r < 4; ++r)
      ybase[(size_t)(4 * g + r) * Cdim + nf2 * 16 + l16] = (__bf16)(o[nf2][r] * inv[r]);
}

// ---- 3) output GEMM: out = Y @ Wout  (m97 structure) -----------------------
// Yb [8192][2048] bf16 row-major, Wt [2048][2048] bf16 (B^T), O f32.
__global__ __launch_bounds__(256) void out_gemm(
    const __bf16* __restrict__ Yb, const __bf16* __restrict__ Wt,
    float* __restrict__ O)
{
  __shared__ struct { __bf16 A[128][32]; __bf16 B[128][32]; } sm;

  const int tid = threadIdx.x, lane = tid & 63, wid = tid >> 6;
  const int g = lane >> 4, l16 = lane & 15;
  const int wr = wid >> 1, wc = wid & 1;
  const int m0 = blockIdx.y * 128, n0 = blockIdx.x * 128;

  const __bf16* gA = Yb + (size_t)(m0 + wid * 32 + (lane >> 2)) * Cdim + (lane & 3) * 8;
  const __bf16* gB = Wt + (size_t)(n0 + wid * 32 + (lane >> 2)) * Cdim + (lane & 3) * 8;
  __bf16* lA0 = &sm.A[wid * 32][0];
  __bf16* lA1 = &sm.A[wid * 32 + 16][0];
  __bf16* lB0 = &sm.B[wid * 32][0];
  __bf16* lB1 = &sm.B[wid * 32 + 16][0];

  f32x4 acc[4][4] = {};

  for (int k0 = 0; k0 < Cdim; k0 += 32) {
    __syncthreads();
    gl16(gA + k0,             lA0);
    gl16(gA + k0 + 16 * Cdim, lA1);
    gl16(gB + k0,             lB0);
    gl16(gB + k0 + 16 * Cdim, lB1);
    __syncthreads();

    bf16x8 a[4], b[4];
    #pragma unroll
    for (int i = 0; i < 4; ++i) {
      a[i] = *(const bf16x8*)&sm.A[wr * 64 + i * 16 + l16][8 * g];
      b[i] = *(const bf16x8*)&sm.B[wc * 64 + i * 16 + l16][8 * g];
    }
    #pragma unroll
    for (int mf = 0; mf < 4; ++mf)
      #pragma unroll
      for (int nf = 0; nf < 4; ++nf)
        acc[mf][nf] = mfma16(a[mf], b[nf], acc[mf][nf]);
  }

  #pragma unroll
  for (int mf = 0; mf < 4; ++mf)
    #pragma unroll
    for (int nf = 0; nf < 4; ++nf)
      #pragma unroll
      for (int r = 0; r < 4; ++r)
        O[(size_t)(m0 + wr * 64 + mf * 16 + g * 4 + r) * Cdim
          + (n0 + wc * 64 + nf * 16 + l16)] = acc[mf][nf][r];
}

// ---- launch -----------------------------------------------------------------
extern "C" void kernel_launch(void* const* d_in, const int* in_sizes, int n_in,
                              void* d_out, int out_size, void* d_ws, size_t ws_size,
                              hipStream_t stream) {
  const float* x    = (const float*)d_in[0];
  const float* Wqkv = (const float*)d_in[1];
  const float* Wout = (const float*)d_in[2];
  float* out = (float*)d_out;

  // workspace layout (~161 MB)
  float*  cosT   = (float*)d_ws;
  float*  sinT   = cosT + Tlen * 64;
  __bf16* Xb     = (__bf16*)(sinT + Tlen * 64);            // 32MB (reused as Y)
  __bf16* Wqkv_t = Xb + (size_t)Mrows * Cdim;              // 24MB [6144][2048]
  __bf16* Wout_t = Wqkv_t + (size_t)N_QKV * Cdim;          // 8MB  [2048][2048]
  __bf16* Qb     = Wout_t + (size_t)Cdim * Cdim;           // 32MB
  __bf16* Kb     = Qb + (size_t)Bsz * Hn * Tlen * Dh;      // 32MB
  __bf16* Vb     = Kb + (size_t)Bsz * Hn * Tlen * Dh;      // 32MB
  __bf16* Yb     = Xb;                                     // reuse (X dead after qkv)

  rope_table_k<<<dim3(512), dim3(256), 0, stream>>>(cosT, sinT);
  f32_to_bf16_k<<<dim3(Mrows * Cdim / (256 * 8)), dim3(256), 0, stream>>>(x, Xb);
  transpose_to_bf16_k<<<dim3(N_QKV / 32, Cdim / 32), dim3(256), 0, stream>>>(
      Wqkv, Wqkv_t, Cdim, N_QKV);
  transpose_to_bf16_k<<<dim3(Cdim / 32, Cdim / 32), dim3(256), 0, stream>>>(
      Wout, Wout_t, Cdim, Cdim);
  qkv_gemm<<<dim3(N_QKV / 128, Mrows / 128), dim3(256), 0, stream>>>(
      Xb, Wqkv_t, Qb, Kb, Vb, cosT, sinT);
  attn_fwd<<<dim3(Tlen / 64, Hn, Bsz), dim3(256), 0, stream>>>(Qb, Kb, Vb, Yb);
  out_gemm<<<dim3(Cdim / 128, Mrows / 128), dim3(256), 0, stream>>>(Yb, Wout_t, out);
}

// Round 3
// 1041.323 us; speedup vs baseline: 1.5096x; 1.3560x over previous
//
#include <hip/hip_runtime.h>
#include <hip/hip_bf16.h>
#include <cmath>

// ---- constants -------------------------------------------------------------
#define Bsz   4
#define Tlen  2048
#define Cdim  2048
#define Hn    16
#define Dh    128
#define N_QKV 6144
#define Mrows 8192          // B*T

typedef __bf16 bf16x8 __attribute__((ext_vector_type(8)));
typedef __bf16 bf16x4 __attribute__((ext_vector_type(4)));
typedef float  f32x4  __attribute__((ext_vector_type(4)));

__device__ __forceinline__ f32x4 mfma16(bf16x8 a, bf16x8 b, f32x4 c) {
  return __builtin_amdgcn_mfma_f32_16x16x32_bf16(a, b, c, 0, 0, 0);
}

__device__ __forceinline__ void gl16(const void* g, void* l) {
  __builtin_amdgcn_global_load_lds(
      (const __attribute__((address_space(1))) void*)g,
      (__attribute__((address_space(3))) void*)l, 16, 0, 0);
}

// ---- 0) RoPE cos/sin table: [T][64] each ----------------------------------
__global__ void rope_table_k(float* __restrict__ cosT, float* __restrict__ sinT) {
  int idx = blockIdx.x * 256 + threadIdx.x;
  int t = idx >> 6, i = idx & 63;
  float invf = __expf(-(float)i * 0.14391156698f);   // 10000^(-i/64)
  float a = (float)t * invf;
  float s, c;
  sincosf(a, &s, &c);
  cosT[idx] = c;
  sinT[idx] = s;
}

// ---- 0b) X fp32 -> bf16 (row-major) ----------------------------------------
__global__ __launch_bounds__(256) void f32_to_bf16_k(
    const float* __restrict__ src, __bf16* __restrict__ dst) {
  size_t i = ((size_t)blockIdx.x * 256 + threadIdx.x) * 8;
  f32x4 a = *(const f32x4*)(src + i);
  f32x4 b = *(const f32x4*)(src + i + 4);
  bf16x8 o;
  o[0] = (__bf16)a[0]; o[1] = (__bf16)a[1]; o[2] = (__bf16)a[2]; o[3] = (__bf16)a[3];
  o[4] = (__bf16)b[0]; o[5] = (__bf16)b[1]; o[6] = (__bf16)b[2]; o[7] = (__bf16)b[3];
  *(bf16x8*)(dst + i) = o;
}

// ---- 0c) W fp32 [K][N] -> bf16 [N][K] (B^T form) ---------------------------
__global__ __launch_bounds__(256) void transpose_to_bf16_k(
    const float* __restrict__ src, __bf16* __restrict__ dst, int K, int N) {
  __shared__ float tile[32][33];
  int n0 = blockIdx.x * 32, k0 = blockIdx.y * 32;
  int tr = threadIdx.x >> 3, tc = (threadIdx.x & 7) * 4;
  f32x4 v = *(const f32x4*)&src[(size_t)(k0 + tr) * N + n0 + tc];
  tile[tr][tc + 0] = v[0]; tile[tr][tc + 1] = v[1];
  tile[tr][tc + 2] = v[2]; tile[tr][tc + 3] = v[3];
  __syncthreads();
  bf16x4 w;
  w[0] = (__bf16)tile[tc + 0][tr];
  w[1] = (__bf16)tile[tc + 1][tr];
  w[2] = (__bf16)tile[tc + 2][tr];
  w[3] = (__bf16)tile[tc + 3][tr];
  *(bf16x4*)&dst[(size_t)(n0 + tr) * K + k0 + tc] = w;
}

// ---- 1) QKV GEMM: 128x128 tile, BK=64, dbuf, swizzled LDS, RoPE epilogue ---
// Xb [8192][2048] bf16, Wt [6144][2048] bf16 (B^T). out [B][H][T][D].
__global__ __launch_bounds__(256) void qkv_gemm(
    const __bf16* __restrict__ Xb, const __bf16* __restrict__ Wt,
    __bf16* __restrict__ Qo, __bf16* __restrict__ Ko, __bf16* __restrict__ Vo,
    const float* __restrict__ cosT, const float* __restrict__ sinT)
{
  __shared__ union SM {
    struct { __bf16 A[2][128][64]; __bf16 B[2][128][64]; } s;  // 64 KB dbuf
    float C[64][132];                                          // epilogue half
  } sm;

  const int tid = threadIdx.x, lane = tid & 63, wid = tid >> 6;
  const int g = lane >> 4, l16 = lane & 15;
  const int wr = wid >> 1, wc = wid & 1;

  // XCD-bijective block swizzle (nwg = 3072, %8 == 0)
  const int nwg = gridDim.x;
  const int swz = (blockIdx.x & 7) * (nwg >> 3) + (blockIdx.x >> 3);
  const int bx = swz % 48, by = swz / 48;
  const int m0 = by * 128, n0 = bx * 128;

  // staging: wave w covers rows w*32..w*32+31; lane l -> rel_row l>>3,
  // global chunk pre-swizzled so linear LDS ends up XOR-swizzled.
  const int srow = lane >> 3;               // 0..7
  const int schk = (lane & 7) ^ srow;       // global 16B-chunk index
  const __bf16* gA = Xb + (size_t)(m0 + wid * 32 + srow) * Cdim + schk * 8;
  const __bf16* gB = Wt + (size_t)(n0 + wid * 32 + srow) * Cdim + schk * 8;

  f32x4 acc[4][4] = {};

  // prologue: stage K-tile 0 into buf 0
  #pragma unroll
  for (int i = 0; i < 4; ++i) {
    gl16(gA + (size_t)i * 8 * Cdim, &sm.s.A[0][wid * 32 + i * 8][0]);
    gl16(gB + (size_t)i * 8 * Cdim, &sm.s.B[0][wid * 32 + i * 8][0]);
  }
  __syncthreads();

  const int NT = Cdim / 64;   // 32 K-tiles
  int cur = 0;
  for (int t = 0; t < NT; ++t) {
    if (t + 1 < NT) {              // issue next-tile stage first (overlaps MFMA)
      const __bf16* pA = gA + (size_t)(t + 1) * 64;
      const __bf16* pB = gB + (size_t)(t + 1) * 64;
      #pragma unroll
      for (int i = 0; i < 4; ++i) {
        gl16(pA + (size_t)i * 8 * Cdim, &sm.s.A[cur ^ 1][wid * 32 + i * 8][0]);
        gl16(pB + (size_t)i * 8 * Cdim, &sm.s.B[cur ^ 1][wid * 32 + i * 8][0]);
      }
    }
    #pragma unroll
    for (int ks = 0; ks < 2; ++ks) {
      bf16x8 a[4], b[4];
      #pragma unroll
      for (int f = 0; f < 4; ++f) {
        // logical chunk (ks*4+g) stored at chunk ^ (row&7); row&7 == l16&7
        const int ca = ((((ks << 2) | g) ^ (l16 & 7)) << 3);
        a[f] = *(const bf16x8*)&sm.s.A[cur][wr * 64 + f * 16 + l16][ca];
        b[f] = *(const bf16x8*)&sm.s.B[cur][wc * 64 + f * 16 + l16][ca];
      }
      #pragma unroll
      for (int mf = 0; mf < 4; ++mf)
        #pragma unroll
        for (int nf = 0; nf < 4; ++nf)
          acc[mf][nf] = mfma16(a[mf], b[nf], acc[mf][nf]);
    }
    __syncthreads();               // drains vmcnt: next tile landed
    cur ^= 1;
  }

  // epilogue: two 64-row halves through LDS f32, RoPE, bf16 store
  const int sel = n0 >> 11;           // 0=q 1=k 2=v
  const int h   = (n0 & 2047) >> 7;
  __bf16* dst = (sel == 0) ? Qo : (sel == 1) ? Ko : Vo;
  const int row = tid >> 2, jb = (tid & 3) * 16;

  #pragma unroll
  for (int rh = 0; rh < 2; ++rh) {
    __syncthreads();
    if (wr == rh) {
      #pragma unroll
      for (int mf = 0; mf < 4; ++mf)
        #pragma unroll
        for (int nf = 0; nf < 4; ++nf)
          #pragma unroll
          for (int r = 0; r < 4; ++r)
            sm.C[mf * 16 + g * 4 + r][wc * 64 + nf * 16 + l16] = acc[mf][nf][r];
    }
    __syncthreads();
    int m = m0 + rh * 64 + row;
    int b_ = m >> 11, t = m & 2047;
    __bf16* out = dst + (((size_t)(b_ * Hn + h)) * Tlen + t) * Dh;
    const float* cb = cosT + t * 64 + jb;
    const float* sb = sinT + t * 64 + jb;
    bf16x8 o1[2], o2[2];
    #pragma unroll
    for (int i = 0; i < 16; ++i) {
      float v1 = sm.C[row][jb + i];
      float v2 = sm.C[row][jb + i + 64];
      float r1, r2;
      if (sel == 2) { r1 = v1; r2 = v2; }
      else {
        float cs = cb[i], sn = sb[i];
        r1 = v1 * cs - v2 * sn;
        r2 = v2 * cs + v1 * sn;
      }
      o1[i >> 3][i & 7] = (__bf16)r1;
      o2[i >> 3][i & 7] = (__bf16)r2;
    }
    *(bf16x8*)&out[jb]      = o1[0];
    *(bf16x8*)&out[jb + 8]  = o1[1];
    *(bf16x8*)&out[jb + 64] = o2[0];
    *(bf16x8*)&out[jb + 72] = o2[1];
  }
}

// ---- 2) Flash attention (causal) -------------------------------------------
__global__ __launch_bounds__(256) void attn_fwd(
    const __bf16* __restrict__ Qg, const __bf16* __restrict__ Kg,
    const __bf16* __restrict__ Vg, __bf16* __restrict__ Yg)
{
  __shared__ __bf16 Qs[64][136];
  __shared__ __bf16 Ks[64][136];
  __shared__ __bf16 Vt[128][72];
  __shared__ __bf16 Ps[4][16][72];

  const int tid  = threadIdx.x;
  const int lane = tid & 63;
  const int wid  = tid >> 6;
  const int g    = lane >> 4, l16 = lane & 15;
  const int q0   = blockIdx.x * 64;
  const size_t bh = ((size_t)blockIdx.z * Hn + blockIdx.y) * Tlen;

  const int sr = tid >> 2, sc = (tid & 3) * 32;

  {
    const bf16x8* src = (const bf16x8*)(Qg + (bh + q0 + sr) * Dh + sc);
    #pragma unroll
    for (int u = 0; u < 4; ++u) *(bf16x8*)&Qs[sr][sc + u * 8] = src[u];
  }

  float m_r[4] = {-1e30f, -1e30f, -1e30f, -1e30f};
  float l_r[4] = {0.f, 0.f, 0.f, 0.f};
  f32x4 o[8] = {};
  const int qrow_w = wid * 16;

  for (int kv0 = 0; kv0 <= q0; kv0 += 64) {
    __syncthreads();
    {
      const bf16x8* ksrc = (const bf16x8*)(Kg + (bh + kv0 + sr) * Dh + sc);
      #pragma unroll
      for (int u = 0; u < 4; ++u) *(bf16x8*)&Ks[sr][sc + u * 8] = ksrc[u];
      const bf16x8* vsrc = (const bf16x8*)(Vg + (bh + kv0 + sr) * Dh + sc);
      #pragma unroll
      for (int u = 0; u < 4; ++u) {
        bf16x8 vv = vsrc[u];
        #pragma unroll
        for (int j = 0; j < 8; ++j) Vt[sc + u * 8 + j][sr] = vv[j];
      }
    }
    __syncthreads();

    f32x4 s[4] = {};
    #pragma unroll
    for (int ks = 0; ks < 4; ++ks) {
      bf16x8 aq = *(const bf16x8*)&Qs[qrow_w + l16][ks * 32 + 8 * g];
      #pragma unroll
      for (int nf = 0; nf < 4; ++nf) {
        bf16x8 bk = *(const bf16x8*)&Ks[nf * 16 + l16][ks * 32 + 8 * g];
        s[nf] = mfma16(aq, bk, s[nf]);
      }
    }

    const float scl = 0.08838834764831845f;
    const bool diag = (kv0 == q0);
    float mx[4];
    #pragma unroll
    for (int r = 0; r < 4; ++r) {
      #pragma unroll
      for (int nf = 0; nf < 4; ++nf) {
        float v = s[nf][r] * scl;
        int qrow = qrow_w + 4 * g + r;
        if (diag && (nf * 16 + l16) > qrow) v = -1e30f;
        s[nf][r] = v;
      }
      mx[r] = fmaxf(fmaxf(s[0][r], s[1][r]), fmaxf(s[2][r], s[3][r]));
    }
    #pragma unroll
    for (int off = 1; off < 16; off <<= 1) {
      #pragma unroll
      for (int r = 0; r < 4; ++r) mx[r] = fmaxf(mx[r], __shfl_xor(mx[r], off, 64));
    }

    float al[4], rs[4];
    #pragma unroll
    for (int r = 0; r < 4; ++r) {
      float mn = fmaxf(m_r[r], mx[r]);
      al[r] = __expf(m_r[r] - mn);
      m_r[r] = mn;
      rs[r] = 0.f;
    }
    #pragma unroll
    for (int nf = 0; nf < 4; ++nf)
      #pragma unroll
      for (int r = 0; r < 4; ++r) {
        float p = __expf(s[nf][r] - m_r[r]);
        s[nf][r] = p;
        rs[r] += p;
      }
    #pragma unroll
    for (int off = 1; off < 16; off <<= 1) {
      #pragma unroll
      for (int r = 0; r < 4; ++r) rs[r] += __shfl_xor(rs[r], off, 64);
    }
    #pragma unroll
    for (int r = 0; r < 4; ++r) l_r[r] = l_r[r] * al[r] + rs[r];
    #pragma unroll
    for (int nf2 = 0; nf2 < 8; ++nf2)
      #pragma unroll
      for (int r = 0; r < 4; ++r) o[nf2][r] *= al[r];

    #pragma unroll
    for (int nf = 0; nf < 4; ++nf)
      #pragma unroll
      for (int r = 0; r < 4; ++r)
        Ps[wid][4 * g + r][nf * 16 + l16] = (__bf16)s[nf][r];
    __syncthreads();

    bf16x8 pa0 = *(const bf16x8*)&Ps[wid][l16][8 * g];
    bf16x8 pa1 = *(const bf16x8*)&Ps[wid][l16][32 + 8 * g];
    #pragma unroll
    for (int nf2 = 0; nf2 < 8; ++nf2) {
      bf16x8 vb0 = *(const bf16x8*)&Vt[nf2 * 16 + l16][8 * g];
      bf16x8 vb1 = *(const bf16x8*)&Vt[nf2 * 16 + l16][32 + 8 * g];
      o[nf2] = mfma16(pa0, vb0, o[nf2]);
      o[nf2] = mfma16(pa1, vb1, o[nf2]);
    }
  }

  float inv[4];
  #pragma unroll
  for (int r = 0; r < 4; ++r) inv[r] = 1.0f / l_r[r];
  __bf16* ybase = Yg + ((size_t)(blockIdx.z * Tlen + q0 + qrow_w)) * Cdim
                + blockIdx.y * Dh;
  #pragma unroll
  for (int nf2 = 0; nf2 < 8; ++nf2)
    #pragma unroll
    for (int r = 0; r < 4; ++r)
      ybase[(size_t)(4 * g + r) * Cdim + nf2 * 16 + l16] = (__bf16)(o[nf2][r] * inv[r]);
}

// ---- 3) output GEMM: 128x128, BK=64, dbuf, swizzled LDS --------------------
__global__ __launch_bounds__(256) void out_gemm(
    const __bf16* __restrict__ Yb, const __bf16* __restrict__ Wt,
    float* __restrict__ O)
{
  __shared__ struct { __bf16 A[2][128][64]; __bf16 B[2][128][64]; } sm;

  const int tid = threadIdx.x, lane = tid & 63, wid = tid >> 6;
  const int g = lane >> 4, l16 = lane & 15;
  const int wr = wid >> 1, wc = wid & 1;

  const int nwg = gridDim.x;          // 1024, %8 == 0
  const int swz = (blockIdx.x & 7) * (nwg >> 3) + (blockIdx.x >> 3);
  const int bx = swz % 16, by = swz / 16;
  const int m0 = by * 128, n0 = bx * 128;

  const int srow = lane >> 3;
  const int schk = (lane & 7) ^ srow;
  const __bf16* gA = Yb + (size_t)(m0 + wid * 32 + srow) * Cdim + schk * 8;
  const __bf16* gB = Wt + (size_t)(n0 + wid * 32 + srow) * Cdim + schk * 8;

  f32x4 acc[4][4] = {};

  #pragma unroll
  for (int i = 0; i < 4; ++i) {
    gl16(gA + (size_t)i * 8 * Cdim, &sm.A[0][wid * 32 + i * 8][0]);
    gl16(gB + (size_t)i * 8 * Cdim, &sm.B[0][wid * 32 + i * 8][0]);
  }
  __syncthreads();

  const int NT = Cdim / 64;
  int cur = 0;
  for (int t = 0; t < NT; ++t) {
    if (t + 1 < NT) {
      const __bf16* pA = gA + (size_t)(t + 1) * 64;
      const __bf16* pB = gB + (size_t)(t + 1) * 64;
      #pragma unroll
      for (int i = 0; i < 4; ++i) {
        gl16(pA + (size_t)i * 8 * Cdim, &sm.A[cur ^ 1][wid * 32 + i * 8][0]);
        gl16(pB + (size_t)i * 8 * Cdim, &sm.B[cur ^ 1][wid * 32 + i * 8][0]);
      }
    }
    #pragma unroll
    for (int ks = 0; ks < 2; ++ks) {
      bf16x8 a[4], b[4];
      #pragma unroll
      for (int f = 0; f < 4; ++f) {
        const int ca = ((((ks << 2) | g) ^ (l16 & 7)) << 3);
        a[f] = *(const bf16x8*)&sm.A[cur][wr * 64 + f * 16 + l16][ca];
        b[f] = *(const bf16x8*)&sm.B[cur][wc * 64 + f * 16 + l16][ca];
      }
      #pragma unroll
      for (int mf = 0; mf < 4; ++mf)
        #pragma unroll
        for (int nf = 0; nf < 4; ++nf)
          acc[mf][nf] = mfma16(a[mf], b[nf], acc[mf][nf]);
    }
    __syncthreads();
    cur ^= 1;
  }

  #pragma unroll
  for (int mf = 0; mf < 4; ++mf)
    #pragma unroll
    for (int nf = 0; nf < 4; ++nf)
      #pragma unroll
      for (int r = 0; r < 4; ++r)
        O[(size_t)(m0 + wr * 64 + mf * 16 + g * 4 + r) * Cdim
          + (n0 + wc * 64 + nf * 16 + l16)] = acc[mf][nf][r];
}

// ---- launch -----------------------------------------------------------------
extern "C" void kernel_launch(void* const* d_in, const int* in_sizes, int n_in,
                              void* d_out, int out_size, void* d_ws, size_t ws_size,
                              hipStream_t stream) {
  const float* x    = (const float*)d_in[0];
  const float* Wqkv = (const float*)d_in[1];
  const float* Wout = (const float*)d_in[2];
  float* out = (float*)d_out;

  float*  cosT   = (float*)d_ws;
  float*  sinT   = cosT + Tlen * 64;
  __bf16* Xb     = (__bf16*)(sinT + Tlen * 64);            // 32MB (reused as Y)
  __bf16* Wqkv_t = Xb + (size_t)Mrows * Cdim;              // 24MB [6144][2048]
  __bf16* Wout_t = Wqkv_t + (size_t)N_QKV * Cdim;          // 8MB  [2048][2048]
  __bf16* Qb     = Wout_t + (size_t)Cdim * Cdim;           // 32MB
  __bf16* Kb     = Qb + (size_t)Bsz * Hn * Tlen * Dh;      // 32MB
  __bf16* Vb     = Kb + (size_t)Bsz * Hn * Tlen * Dh;      // 32MB
  __bf16* Yb     = Xb;

  rope_table_k<<<dim3(512), dim3(256), 0, stream>>>(cosT, sinT);
  f32_to_bf16_k<<<dim3(Mrows * Cdim / (256 * 8)), dim3(256), 0, stream>>>(x, Xb);
  transpose_to_bf16_k<<<dim3(N_QKV / 32, Cdim / 32), dim3(256), 0, stream>>>(
      Wqkv, Wqkv_t, Cdim, N_QKV);
  transpose_to_bf16_k<<<dim3(Cdim / 32, Cdim / 32), dim3(256), 0, stream>>>(
      Wout, Wout_t, Cdim, Cdim);
  qkv_gemm<<<dim3(3072), dim3(256), 0, stream>>>(
      Xb, Wqkv_t, Qb, Kb, Vb, cosT, sinT);
  attn_fwd<<<dim3(Tlen / 64, Hn, Bsz), dim3(256), 0, stream>>>(Qb, Kb, Vb, Yb);
  out_gemm<<<dim3(1024), dim3(256), 0, stream>>>(Yb, Wout_t, out);
}

// Round 5
// 1012.914 us; speedup vs baseline: 1.5520x; 1.0280x over previous
//
#include <hip/hip_runtime.h>
#include <hip/hip_bf16.h>
#include <cmath>

// ---- constants -------------------------------------------------------------
#define Bsz   4
#define Tlen  2048
#define Cdim  2048
#define Hn    16
#define Dh    128
#define N_QKV 6144
#define Mrows 8192          // B*T

typedef __bf16 bf16x8 __attribute__((ext_vector_type(8)));
typedef __bf16 bf16x4 __attribute__((ext_vector_type(4)));
typedef float  f32x4  __attribute__((ext_vector_type(4)));

__device__ __forceinline__ f32x4 mfma16(bf16x8 a, bf16x8 b, f32x4 c) {
  return __builtin_amdgcn_mfma_f32_16x16x32_bf16(a, b, c, 0, 0, 0);
}

__device__ __forceinline__ void gl16(const void* g, void* l) {
  __builtin_amdgcn_global_load_lds(
      (const __attribute__((address_space(1))) void*)g,
      (__attribute__((address_space(3))) void*)l, 16, 0, 0);
}

// ---- 0) RoPE cos/sin table: [T][64] each ----------------------------------
__global__ void rope_table_k(float* __restrict__ cosT, float* __restrict__ sinT) {
  int idx = blockIdx.x * 256 + threadIdx.x;
  int t = idx >> 6, i = idx & 63;
  float invf = __expf(-(float)i * 0.14391156698f);   // 10000^(-i/64)
  float a = (float)t * invf;
  float s, c;
  sincosf(a, &s, &c);
  cosT[idx] = c;
  sinT[idx] = s;
}

// ---- 0b) X fp32 -> bf16 (row-major) ----------------------------------------
__global__ __launch_bounds__(256) void f32_to_bf16_k(
    const float* __restrict__ src, __bf16* __restrict__ dst) {
  size_t i = ((size_t)blockIdx.x * 256 + threadIdx.x) * 8;
  f32x4 a = *(const f32x4*)(src + i);
  f32x4 b = *(const f32x4*)(src + i + 4);
  bf16x8 o;
  o[0] = (__bf16)a[0]; o[1] = (__bf16)a[1]; o[2] = (__bf16)a[2]; o[3] = (__bf16)a[3];
  o[4] = (__bf16)b[0]; o[5] = (__bf16)b[1]; o[6] = (__bf16)b[2]; o[7] = (__bf16)b[3];
  *(bf16x8*)(dst + i) = o;
}

// ---- 0c) W fp32 [K][N] -> bf16 [N][K] (B^T form) ---------------------------
__global__ __launch_bounds__(256) void transpose_to_bf16_k(
    const float* __restrict__ src, __bf16* __restrict__ dst, int K, int N) {
  __shared__ float tile[32][33];
  int n0 = blockIdx.x * 32, k0 = blockIdx.y * 32;
  int tr = threadIdx.x >> 3, tc = (threadIdx.x & 7) * 4;
  f32x4 v = *(const f32x4*)&src[(size_t)(k0 + tr) * N + n0 + tc];
  tile[tr][tc + 0] = v[0]; tile[tr][tc + 1] = v[1];
  tile[tr][tc + 2] = v[2]; tile[tr][tc + 3] = v[3];
  __syncthreads();
  bf16x4 w;
  w[0] = (__bf16)tile[tc + 0][tr];
  w[1] = (__bf16)tile[tc + 1][tr];
  w[2] = (__bf16)tile[tc + 2][tr];
  w[3] = (__bf16)tile[tc + 3][tr];
  *(bf16x4*)&dst[(size_t)(n0 + tr) * K + k0 + tc] = w;
}

// ---- 1) QKV GEMM: 128x128, BK=64, counted-vmcnt dbuf, swizzled LDS ---------
// Xb [8192][2048] bf16, Wt [6144][2048] bf16 (B^T). out [B][H][T][D].
__global__ __launch_bounds__(256) void qkv_gemm(
    const __bf16* __restrict__ Xb, const __bf16* __restrict__ Wt,
    __bf16* __restrict__ Qo, __bf16* __restrict__ Ko, __bf16* __restrict__ Vo,
    const float* __restrict__ cosT, const float* __restrict__ sinT)
{
  __shared__ union SM {
    struct { __bf16 A[2][128][64]; __bf16 B[2][128][64]; } s;  // 64 KB dbuf
    float C[64][132];                                          // epilogue half
  } sm;

  const int tid = threadIdx.x, lane = tid & 63, wid = tid >> 6;
  const int g = lane >> 4, l16 = lane & 15;
  const int wr = wid >> 1, wc = wid & 1;

  // 8x8 supertile per XCD (bijective): grid 3072 = 48 bx * 64 by
  const int bid = blockIdx.x;
  const int xcd = bid & 7, s_ = bid >> 3;           // s_ in 0..383
  const int stl = s_ >> 6, pos = s_ & 63;           // 6 supertiles/XCD
  const int st  = xcd * 6 + stl;                    // 0..47 (8 sty x 6 stx)
  const int sty = st / 6, stx = st % 6;
  const int by = sty * 8 + (pos >> 3), bx = stx * 8 + (pos & 7);
  const int m0 = by * 128, n0 = bx * 128;

  const int srow = lane >> 3;               // 0..7
  const int schk = (lane & 7) ^ srow;       // pre-swizzled global 16B chunk
  const __bf16* gA = Xb + (size_t)(m0 + wid * 32 + srow) * Cdim + schk * 8;
  const __bf16* gB = Wt + (size_t)(n0 + wid * 32 + srow) * Cdim + schk * 8;

  f32x4 acc[4][4] = {};
  const int NT = Cdim / 64;   // 32 K-tiles

  // prologue: stage tiles 0 and 1 (16 loads outstanding per thread)
  #pragma unroll
  for (int i = 0; i < 4; ++i) {
    gl16(gA + (size_t)i * 8 * Cdim, &sm.s.A[0][wid * 32 + i * 8][0]);
    gl16(gB + (size_t)i * 8 * Cdim, &sm.s.B[0][wid * 32 + i * 8][0]);
  }
  #pragma unroll
  for (int i = 0; i < 4; ++i) {
    gl16(gA + 64 + (size_t)i * 8 * Cdim, &sm.s.A[1][wid * 32 + i * 8][0]);
    gl16(gB + 64 + (size_t)i * 8 * Cdim, &sm.s.B[1][wid * 32 + i * 8][0]);
  }

  for (int t = 0; t < NT; ++t) {
    const int p = t & 1;
    if (t < NT - 1) asm volatile("s_waitcnt vmcnt(8)" ::: "memory");
    else            asm volatile("s_waitcnt vmcnt(0)" ::: "memory");
    __builtin_amdgcn_s_barrier();
    __builtin_amdgcn_sched_barrier(0);   // pin compute region start

    #pragma unroll
    for (int ks = 0; ks < 2; ++ks) {
      bf16x8 a[4], b[4];
      #pragma unroll
      for (int f = 0; f < 4; ++f) {
        const int ca = ((((ks << 2) | g) ^ (l16 & 7)) << 3);
        a[f] = *(const bf16x8*)&sm.s.A[p][wr * 64 + f * 16 + l16][ca];
        b[f] = *(const bf16x8*)&sm.s.B[p][wc * 64 + f * 16 + l16][ca];
      }
      #pragma unroll
      for (int mf = 0; mf < 4; ++mf)
        #pragma unroll
        for (int nf = 0; nf < 4; ++nf)
          acc[mf][nf] = mfma16(a[mf], b[nf], acc[mf][nf]);
    }

    __builtin_amdgcn_sched_barrier(0);   // pin: MFMAs + lgkm waits stay above
    asm volatile("s_waitcnt lgkmcnt(0)" ::: "memory");  // ds_reads serviced
    __builtin_amdgcn_s_barrier();

    if (t + 2 < NT) {          // stage tile t+2 into the buffer just read
      const __bf16* pA = gA + (size_t)(t + 2) * 64;
      const __bf16* pB = gB + (size_t)(t + 2) * 64;
      #pragma unroll
      for (int i = 0; i < 4; ++i) {
        gl16(pA + (size_t)i * 8 * Cdim, &sm.s.A[p][wid * 32 + i * 8][0]);
        gl16(pB + (size_t)i * 8 * Cdim, &sm.s.B[p][wid * 32 + i * 8][0]);
      }
    }
  }

  // epilogue: two 64-row halves through LDS f32, RoPE, bf16 store
  const int sel = n0 >> 11;           // 0=q 1=k 2=v
  const int h   = (n0 & 2047) >> 7;
  __bf16* dst = (sel == 0) ? Qo : (sel == 1) ? Ko : Vo;
  const int row = tid >> 2, jb = (tid & 3) * 16;

  #pragma unroll
  for (int rh = 0; rh < 2; ++rh) {
    __syncthreads();
    if (wr == rh) {
      #pragma unroll
      for (int mf = 0; mf < 4; ++mf)
        #pragma unroll
        for (int nf = 0; nf < 4; ++nf)
          #pragma unroll
          for (int r = 0; r < 4; ++r)
            sm.C[mf * 16 + g * 4 + r][wc * 64 + nf * 16 + l16] = acc[mf][nf][r];
    }
    __syncthreads();
    int m = m0 + rh * 64 + row;
    int b_ = m >> 11, t = m & 2047;
    __bf16* out = dst + (((size_t)(b_ * Hn + h)) * Tlen + t) * Dh;
    const float* cb = cosT + t * 64 + jb;
    const float* sb = sinT + t * 64 + jb;
    bf16x8 o1[2], o2[2];
    #pragma unroll
    for (int i = 0; i < 16; ++i) {
      float v1 = sm.C[row][jb + i];
      float v2 = sm.C[row][jb + i + 64];
      float r1, r2;
      if (sel == 2) { r1 = v1; r2 = v2; }
      else {
        float cs = cb[i], sn = sb[i];
        r1 = v1 * cs - v2 * sn;
        r2 = v2 * cs + v1 * sn;
      }
      o1[i >> 3][i & 7] = (__bf16)r1;
      o2[i >> 3][i & 7] = (__bf16)r2;
    }
    *(bf16x8*)&out[jb]      = o1[0];
    *(bf16x8*)&out[jb + 8]  = o1[1];
    *(bf16x8*)&out[jb + 64] = o2[0];
    *(bf16x8*)&out[jb + 72] = o2[1];
  }
}

// ---- 2) Flash attention (causal) -------------------------------------------
__global__ __launch_bounds__(256) void attn_fwd(
    const __bf16* __restrict__ Qg, const __bf16* __restrict__ Kg,
    const __bf16* __restrict__ Vg, __bf16* __restrict__ Yg)
{
  __shared__ __bf16 Qs[64][136];
  __shared__ __bf16 Ks[64][136];
  __shared__ __bf16 Vt[128][72];
  __shared__ __bf16 Ps[4][16][72];

  const int tid  = threadIdx.x;
  const int lane = tid & 63;
  const int wid  = tid >> 6;
  const int g    = lane >> 4, l16 = lane & 15;
  const int q0   = blockIdx.x * 64;
  const size_t bh = ((size_t)blockIdx.z * Hn + blockIdx.y) * Tlen;

  const int sr = tid >> 2, sc = (tid & 3) * 32;

  {
    const bf16x8* src = (const bf16x8*)(Qg + (bh + q0 + sr) * Dh + sc);
    #pragma unroll
    for (int u = 0; u < 4; ++u) *(bf16x8*)&Qs[sr][sc + u * 8] = src[u];
  }

  float m_r[4] = {-1e30f, -1e30f, -1e30f, -1e30f};
  float l_r[4] = {0.f, 0.f, 0.f, 0.f};
  f32x4 o[8] = {};
  const int qrow_w = wid * 16;

  for (int kv0 = 0; kv0 <= q0; kv0 += 64) {
    __syncthreads();
    {
      const bf16x8* ksrc = (const bf16x8*)(Kg + (bh + kv0 + sr) * Dh + sc);
      #pragma unroll
      for (int u = 0; u < 4; ++u) *(bf16x8*)&Ks[sr][sc + u * 8] = ksrc[u];
      const bf16x8* vsrc = (const bf16x8*)(Vg + (bh + kv0 + sr) * Dh + sc);
      #pragma unroll
      for (int u = 0; u < 4; ++u) {
        bf16x8 vv = vsrc[u];
        #pragma unroll
        for (int j = 0; j < 8; ++j) Vt[sc + u * 8 + j][sr] = vv[j];
      }
    }
    __syncthreads();

    f32x4 s[4] = {};
    #pragma unroll
    for (int ks = 0; ks < 4; ++ks) {
      bf16x8 aq = *(const bf16x8*)&Qs[qrow_w + l16][ks * 32 + 8 * g];
      #pragma unroll
      for (int nf = 0; nf < 4; ++nf) {
        bf16x8 bk = *(const bf16x8*)&Ks[nf * 16 + l16][ks * 32 + 8 * g];
        s[nf] = mfma16(aq, bk, s[nf]);
      }
    }

    const float scl = 0.08838834764831845f;
    const bool diag = (kv0 == q0);
    float mx[4];
    #pragma unroll
    for (int r = 0; r < 4; ++r) {
      #pragma unroll
      for (int nf = 0; nf < 4; ++nf) {
        float v = s[nf][r] * scl;
        int qrow = qrow_w + 4 * g + r;
        if (diag && (nf * 16 + l16) > qrow) v = -1e30f;
        s[nf][r] = v;
      }
      mx[r] = fmaxf(fmaxf(s[0][r], s[1][r]), fmaxf(s[2][r], s[3][r]));
    }
    #pragma unroll
    for (int off = 1; off < 16; off <<= 1) {
      #pragma unroll
      for (int r = 0; r < 4; ++r) mx[r] = fmaxf(mx[r], __shfl_xor(mx[r], off, 64));
    }

    float al[4], rs[4];
    #pragma unroll
    for (int r = 0; r < 4; ++r) {
      float mn = fmaxf(m_r[r], mx[r]);
      al[r] = __expf(m_r[r] - mn);
      m_r[r] = mn;
      rs[r] = 0.f;
    }
    #pragma unroll
    for (int nf = 0; nf < 4; ++nf)
      #pragma unroll
      for (int r = 0; r < 4; ++r) {
        float p = __expf(s[nf][r] - m_r[r]);
        s[nf][r] = p;
        rs[r] += p;
      }
    #pragma unroll
    for (int off = 1; off < 16; off <<= 1) {
      #pragma unroll
      for (int r = 0; r < 4; ++r) rs[r] += __shfl_xor(rs[r], off, 64);
    }
    #pragma unroll
    for (int r = 0; r < 4; ++r) l_r[r] = l_r[r] * al[r] + rs[r];
    #pragma unroll
    for (int nf2 = 0; nf2 < 8; ++nf2)
      #pragma unroll
      for (int r = 0; r < 4; ++r) o[nf2][r] *= al[r];

    #pragma unroll
    for (int nf = 0; nf < 4; ++nf)
      #pragma unroll
      for (int r = 0; r < 4; ++r)
        Ps[wid][4 * g + r][nf * 16 + l16] = (__bf16)s[nf][r];
    __syncthreads();

    bf16x8 pa0 = *(const bf16x8*)&Ps[wid][l16][8 * g];
    bf16x8 pa1 = *(const bf16x8*)&Ps[wid][l16][32 + 8 * g];
    #pragma unroll
    for (int nf2 = 0; nf2 < 8; ++nf2) {
      bf16x8 vb0 = *(const bf16x8*)&Vt[nf2 * 16 + l16][8 * g];
      bf16x8 vb1 = *(const bf16x8*)&Vt[nf2 * 16 + l16][32 + 8 * g];
      o[nf2] = mfma16(pa0, vb0, o[nf2]);
      o[nf2] = mfma16(pa1, vb1, o[nf2]);
    }
  }

  float inv[4];
  #pragma unroll
  for (int r = 0; r < 4; ++r) inv[r] = 1.0f / l_r[r];
  __bf16* ybase = Yg + ((size_t)(blockIdx.z * Tlen + q0 + qrow_w)) * Cdim
                + blockIdx.y * Dh;
  #pragma unroll
  for (int nf2 = 0; nf2 < 8; ++nf2)
    #pragma unroll
    for (int r = 0; r < 4; ++r)
      ybase[(size_t)(4 * g + r) * Cdim + nf2 * 16 + l16] = (__bf16)(o[nf2][r] * inv[r]);
}

// ---- 3) output GEMM: 128x128, BK=64, counted-vmcnt dbuf --------------------
__global__ __launch_bounds__(256) void out_gemm(
    const __bf16* __restrict__ Yb, const __bf16* __restrict__ Wt,
    float* __restrict__ O)
{
  __shared__ struct { __bf16 A[2][128][64]; __bf16 B[2][128][64]; } sm;

  const int tid = threadIdx.x, lane = tid & 63, wid = tid >> 6;
  const int g = lane >> 4, l16 = lane & 15;
  const int wr = wid >> 1, wc = wid & 1;

  // 8x8 supertile per XCD: grid 1024 = 16 bx * 64 by
  const int bid = blockIdx.x;
  const int xcd = bid & 7, s_ = bid >> 3;           // 0..127
  const int stl = s_ >> 6, pos = s_ & 63;           // 2 supertiles/XCD
  const int st  = xcd * 2 + stl;                    // 0..15 (8 sty x 2 stx)
  const int sty = st / 2, stx = st % 2;
  const int by = sty * 8 + (pos >> 3), bx = stx * 8 + (pos & 7);
  const int m0 = by * 128, n0 = bx * 128;

  const int srow = lane >> 3;
  const int schk = (lane & 7) ^ srow;
  const __bf16* gA = Yb + (size_t)(m0 + wid * 32 + srow) * Cdim + schk * 8;
  const __bf16* gB = Wt + (size_t)(n0 + wid * 32 + srow) * Cdim + schk * 8;

  f32x4 acc[4][4] = {};
  const int NT = Cdim / 64;

  #pragma unroll
  for (int i = 0; i < 4; ++i) {
    gl16(gA + (size_t)i * 8 * Cdim, &sm.A[0][wid * 32 + i * 8][0]);
    gl16(gB + (size_t)i * 8 * Cdim, &sm.B[0][wid * 32 + i * 8][0]);
  }
  #pragma unroll
  for (int i = 0; i < 4; ++i) {
    gl16(gA + 64 + (size_t)i * 8 * Cdim, &sm.A[1][wid * 32 + i * 8][0]);
    gl16(gB + 64 + (size_t)i * 8 * Cdim, &sm.B[1][wid * 32 + i * 8][0]);
  }

  for (int t = 0; t < NT; ++t) {
    const int p = t & 1;
    if (t < NT - 1) asm volatile("s_waitcnt vmcnt(8)" ::: "memory");
    else            asm volatile("s_waitcnt vmcnt(0)" ::: "memory");
    __builtin_amdgcn_s_barrier();
    __builtin_amdgcn_sched_barrier(0);

    #pragma unroll
    for (int ks = 0; ks < 2; ++ks) {
      bf16x8 a[4], b[4];
      #pragma unroll
      for (int f = 0; f < 4; ++f) {
        const int ca = ((((ks << 2) | g) ^ (l16 & 7)) << 3);
        a[f] = *(const bf16x8*)&sm.A[p][wr * 64 + f * 16 + l16][ca];
        b[f] = *(const bf16x8*)&sm.B[p][wc * 64 + f * 16 + l16][ca];
      }
      #pragma unroll
      for (int mf = 0; mf < 4; ++mf)
        #pragma unroll
        for (int nf = 0; nf < 4; ++nf)
          acc[mf][nf] = mfma16(a[mf], b[nf], acc[mf][nf]);
    }

    __builtin_amdgcn_sched_barrier(0);
    asm volatile("s_waitcnt lgkmcnt(0)" ::: "memory");
    __builtin_amdgcn_s_barrier();

    if (t + 2 < NT) {
      const __bf16* pA = gA + (size_t)(t + 2) * 64;
      const __bf16* pB = gB + (size_t)(t + 2) * 64;
      #pragma unroll
      for (int i = 0; i < 4; ++i) {
        gl16(pA + (size_t)i * 8 * Cdim, &sm.A[p][wid * 32 + i * 8][0]);
        gl16(pB + (size_t)i * 8 * Cdim, &sm.B[p][wid * 32 + i * 8][0]);
      }
    }
  }

  #pragma unroll
  for (int mf = 0; mf < 4; ++mf)
    #pragma unroll
    for (int nf = 0; nf < 4; ++nf)
      #pragma unroll
      for (int r = 0; r < 4; ++r)
        O[(size_t)(m0 + wr * 64 + mf * 16 + g * 4 + r) * Cdim
          + (n0 + wc * 64 + nf * 16 + l16)] = acc[mf][nf][r];
}

// ---- launch -----------------------------------------------------------------
extern "C" void kernel_launch(void* const* d_in, const int* in_sizes, int n_in,
                              void* d_out, int out_size, void* d_ws, size_t ws_size,
                              hipStream_t stream) {
  const float* x    = (const float*)d_in[0];
  const float* Wqkv = (const float*)d_in[1];
  const float* Wout = (const float*)d_in[2];
  float* out = (float*)d_out;

  float*  cosT   = (float*)d_ws;
  float*  sinT   = cosT + Tlen * 64;
  __bf16* Xb     = (__bf16*)(sinT + Tlen * 64);            // 32MB (reused as Y)
  __bf16* Wqkv_t = Xb + (size_t)Mrows * Cdim;              // 24MB [6144][2048]
  __bf16* Wout_t = Wqkv_t + (size_t)N_QKV * Cdim;          // 8MB  [2048][2048]
  __bf16* Qb     = Wout_t + (size_t)Cdim * Cdim;           // 32MB
  __bf16* Kb     = Qb + (size_t)Bsz * Hn * Tlen * Dh;      // 32MB
  __bf16* Vb     = Kb + (size_t)Bsz * Hn * Tlen * Dh;      // 32MB
  __bf16* Yb     = Xb;

  rope_table_k<<<dim3(512), dim3(256), 0, stream>>>(cosT, sinT);
  f32_to_bf16_k<<<dim3(Mrows * Cdim / (256 * 8)), dim3(256), 0, stream>>>(x, Xb);
  transpose_to_bf16_k<<<dim3(N_QKV / 32, Cdim / 32), dim3(256), 0, stream>>>(
      Wqkv, Wqkv_t, Cdim, N_QKV);
  transpose_to_bf16_k<<<dim3(Cdim / 32, Cdim / 32), dim3(256), 0, stream>>>(
      Wout, Wout_t, Cdim, Cdim);
  qkv_gemm<<<dim3(3072), dim3(256), 0, stream>>>(
      Xb, Wqkv_t, Qb, Kb, Vb, cosT, sinT);
  attn_fwd<<<dim3(Tlen / 64, Hn, Bsz), dim3(256), 0, stream>>>(Qb, Kb, Vb, Yb);
  out_gemm<<<dim3(1024), dim3(256), 0, stream>>>(Yb, Wout_t, out);
}

// Round 6
// 872.752 us; speedup vs baseline: 1.8012x; 1.1606x over previous
//
#include <hip/hip_runtime.h>
#include <hip/hip_bf16.h>
#include <cmath>

// ---- constants -------------------------------------------------------------
#define Bsz   4
#define Tlen  2048
#define Cdim  2048
#define Hn    16
#define Dh    128
#define N_QKV 6144
#define Mrows 8192          // B*T

typedef __bf16 bf16x8 __attribute__((ext_vector_type(8)));
typedef __bf16 bf16x4 __attribute__((ext_vector_type(4)));
typedef float  f32x4  __attribute__((ext_vector_type(4)));

__device__ __forceinline__ f32x4 mfma16(bf16x8 a, bf16x8 b, f32x4 c) {
  return __builtin_amdgcn_mfma_f32_16x16x32_bf16(a, b, c, 0, 0, 0);
}

__device__ __forceinline__ void gl16(const void* g, void* l) {
  __builtin_amdgcn_global_load_lds(
      (const __attribute__((address_space(1))) void*)g,
      (__attribute__((address_space(3))) void*)l, 16, 0, 0);
}

// ---- 0) RoPE cos/sin table: [T][64] each ----------------------------------
__global__ void rope_table_k(float* __restrict__ cosT, float* __restrict__ sinT) {
  int idx = blockIdx.x * 256 + threadIdx.x;
  int t = idx >> 6, i = idx & 63;
  float invf = __expf(-(float)i * 0.14391156698f);   // 10000^(-i/64)
  float a = (float)t * invf;
  float s, c;
  sincosf(a, &s, &c);
  cosT[idx] = c;
  sinT[idx] = s;
}

// ---- 0b) X fp32 -> bf16 (row-major) ----------------------------------------
__global__ __launch_bounds__(256) void f32_to_bf16_k(
    const float* __restrict__ src, __bf16* __restrict__ dst) {
  size_t i = ((size_t)blockIdx.x * 256 + threadIdx.x) * 8;
  f32x4 a = *(const f32x4*)(src + i);
  f32x4 b = *(const f32x4*)(src + i + 4);
  bf16x8 o;
  o[0] = (__bf16)a[0]; o[1] = (__bf16)a[1]; o[2] = (__bf16)a[2]; o[3] = (__bf16)a[3];
  o[4] = (__bf16)b[0]; o[5] = (__bf16)b[1]; o[6] = (__bf16)b[2]; o[7] = (__bf16)b[3];
  *(bf16x8*)(dst + i) = o;
}

// ---- 0c) W fp32 [K][N] -> bf16 [N][K] (B^T form) ---------------------------
__global__ __launch_bounds__(256) void transpose_to_bf16_k(
    const float* __restrict__ src, __bf16* __restrict__ dst, int K, int N) {
  __shared__ float tile[32][33];
  int n0 = blockIdx.x * 32, k0 = blockIdx.y * 32;
  int tr = threadIdx.x >> 3, tc = (threadIdx.x & 7) * 4;
  f32x4 v = *(const f32x4*)&src[(size_t)(k0 + tr) * N + n0 + tc];
  tile[tr][tc + 0] = v[0]; tile[tr][tc + 1] = v[1];
  tile[tr][tc + 2] = v[2]; tile[tr][tc + 3] = v[3];
  __syncthreads();
  bf16x4 w;
  w[0] = (__bf16)tile[tc + 0][tr];
  w[1] = (__bf16)tile[tc + 1][tr];
  w[2] = (__bf16)tile[tc + 2][tr];
  w[3] = (__bf16)tile[tc + 3][tr];
  *(bf16x4*)&dst[(size_t)(n0 + tr) * K + k0 + tc] = w;
}

// ---- 1) QKV GEMM: 256x256, 8 waves, BK=64, counted-vmcnt dbuf --------------
// Xb [8192][2048] bf16, Wt [6144][2048] bf16 (B^T). out [B][H][T][D] + RoPE.
__global__ __launch_bounds__(512, 2) void qkv_gemm(
    const __bf16* __restrict__ Xb, const __bf16* __restrict__ Wt,
    __bf16* __restrict__ Qo, __bf16* __restrict__ Ko, __bf16* __restrict__ Vo,
    const float* __restrict__ cosT, const float* __restrict__ sinT)
{
  __shared__ union SM {
    struct { __bf16 A[2][256 * 64]; __bf16 B[2][256 * 64]; } s;  // 128 KB dbuf
    float C[64][265];                                            // epilogue
  } sm;

  const int tid = threadIdx.x, lane = tid & 63, wid = tid >> 6;
  const int g = lane >> 4, l16 = lane & 15;
  const int wr = wid >> 2, wc = wid & 3;       // 2 x 4 wave grid

  // supertile: 768 blocks = 8 xcd * 6 stl * 16 pos; each XCD owns 4 by-rows
  const int bid = blockIdx.x;
  const int xcd = bid & 7, idx = bid >> 3;
  const int stl = idx >> 4, pos = idx & 15;
  const int m0 = (xcd * 4 + (pos >> 2)) * 256;
  const int n0 = (stl * 4 + (pos & 3)) * 256;

  // staging: round r covers rows r*64..r*64+63; source chunk pre-swizzled
  const int srow = tid >> 3;                   // 0..63
  const int schk = (tid & 7) ^ (srow & 7);
  const __bf16* gA = Xb + (size_t)(m0 + srow) * Cdim + schk * 8;
  const __bf16* gB = Wt + (size_t)(n0 + srow) * Cdim + schk * 8;
  const int ldst = wid * 512;                  // + r*4096, lane*8 implicit

  f32x4 acc[8][4] = {};
  const int NT = Cdim / 64;   // 32 K-tiles

  // prologue: stage tiles 0 and 1 (16 loads outstanding per thread)
  #pragma unroll
  for (int r = 0; r < 4; ++r) {
    gl16(gA + (size_t)r * 64 * Cdim, &sm.s.A[0][r * 4096 + ldst]);
    gl16(gB + (size_t)r * 64 * Cdim, &sm.s.B[0][r * 4096 + ldst]);
  }
  #pragma unroll
  for (int r = 0; r < 4; ++r) {
    gl16(gA + 64 + (size_t)r * 64 * Cdim, &sm.s.A[1][r * 4096 + ldst]);
    gl16(gB + 64 + (size_t)r * 64 * Cdim, &sm.s.B[1][r * 4096 + ldst]);
  }

  for (int t = 0; t < NT; ++t) {
    const int p = t & 1;
    if (t < NT - 1) asm volatile("s_waitcnt vmcnt(8)" ::: "memory");
    else            asm volatile("s_waitcnt vmcnt(0)" ::: "memory");
    __builtin_amdgcn_s_barrier();
    __builtin_amdgcn_sched_barrier(0);   // pin compute region start

    #pragma unroll
    for (int kk = 0; kk < 2; ++kk) {
      bf16x8 a[8], b[4];
      const int ch = (((kk << 2) | g) ^ (l16 & 7)) * 8;
      #pragma unroll
      for (int f = 0; f < 8; ++f)
        a[f] = *(const bf16x8*)&sm.s.A[p][(wr * 128 + f * 16 + l16) * 64 + ch];
      #pragma unroll
      for (int n = 0; n < 4; ++n)
        b[n] = *(const bf16x8*)&sm.s.B[p][(wc * 64 + n * 16 + l16) * 64 + ch];
      #pragma unroll
      for (int f = 0; f < 8; ++f)
        #pragma unroll
        for (int n = 0; n < 4; ++n)
          acc[f][n] = mfma16(a[f], b[n], acc[f][n]);
    }

    __builtin_amdgcn_sched_barrier(0);   // MFMAs + lgkm waits stay above
    asm volatile("s_waitcnt lgkmcnt(0)" ::: "memory");
    __builtin_amdgcn_s_barrier();

    if (t + 2 < NT) {                    // stage tile t+2 into buffer just read
      const __bf16* pA = gA + (size_t)(t + 2) * 64;
      const __bf16* pB = gB + (size_t)(t + 2) * 64;
      #pragma unroll
      for (int r = 0; r < 4; ++r) {
        gl16(pA + (size_t)r * 64 * Cdim, &sm.s.A[p][r * 4096 + ldst]);
        gl16(pB + (size_t)r * 64 * Cdim, &sm.s.B[p][r * 4096 + ldst]);
      }
    }
  }

  // epilogue: four 64-row rounds through LDS f32, RoPE, bf16 store
  const int sel = n0 >> 11;             // 0=q 1=k 2=v (tile never spans)
  const int h0  = (n0 & 2047) >> 7;     // first of 2 heads in this tile
  __bf16* dst = (sel == 0) ? Qo : (sel == 1) ? Ko : Vo;
  const int erow = tid >> 3, q = tid & 7;
  const int dlo = (q & 3) * 16;               // 0..48
  const int clo = (q >> 2) * 128 + dlo;       // tile col of the d<64 half

  #pragma unroll
  for (int rh = 0; rh < 4; ++rh) {
    if (wr == (rh >> 1)) {
      const int fb = (rh & 1) * 4;
      #pragma unroll
      for (int f2 = 0; f2 < 4; ++f2)
        #pragma unroll
        for (int n = 0; n < 4; ++n)
          #pragma unroll
          for (int r = 0; r < 4; ++r)
            sm.C[f2 * 16 + g * 4 + r][wc * 64 + n * 16 + l16] = acc[fb + f2][n][r];
    }
    __syncthreads();
    const int m = m0 + rh * 64 + erow;
    const int b_ = m >> 11, t = m & 2047;
    __bf16* out = dst + (((size_t)(b_ * Hn + h0 + (q >> 2))) * Tlen + t) * Dh + dlo;
    const float* cb = cosT + t * 64 + dlo;
    const float* sb = sinT + t * 64 + dlo;
    bf16x8 o1[2], o2[2];
    #pragma unroll
    for (int i = 0; i < 16; ++i) {
      float v1 = sm.C[erow][clo + i];
      float v2 = sm.C[erow][clo + i + 64];
      float r1, r2;
      if (sel == 2) { r1 = v1; r2 = v2; }
      else {
        float cs = cb[i], sn = sb[i];
        r1 = v1 * cs - v2 * sn;
        r2 = v2 * cs + v1 * sn;
      }
      o1[i >> 3][i & 7] = (__bf16)r1;
      o2[i >> 3][i & 7] = (__bf16)r2;
    }
    *(bf16x8*)&out[0]  = o1[0];
    *(bf16x8*)&out[8]  = o1[1];
    *(bf16x8*)&out[64] = o2[0];
    *(bf16x8*)&out[72] = o2[1];
    __syncthreads();
  }
}

// ---- 2) Flash attention (causal) — unchanged from round 5 ------------------
__global__ __launch_bounds__(256) void attn_fwd(
    const __bf16* __restrict__ Qg, const __bf16* __restrict__ Kg,
    const __bf16* __restrict__ Vg, __bf16* __restrict__ Yg)
{
  __shared__ __bf16 Qs[64][136];
  __shared__ __bf16 Ks[64][136];
  __shared__ __bf16 Vt[128][72];
  __shared__ __bf16 Ps[4][16][72];

  const int tid  = threadIdx.x;
  const int lane = tid & 63;
  const int wid  = tid >> 6;
  const int g    = lane >> 4, l16 = lane & 15;
  const int q0   = blockIdx.x * 64;
  const size_t bh = ((size_t)blockIdx.z * Hn + blockIdx.y) * Tlen;

  const int sr = tid >> 2, sc = (tid & 3) * 32;

  {
    const bf16x8* src = (const bf16x8*)(Qg + (bh + q0 + sr) * Dh + sc);
    #pragma unroll
    for (int u = 0; u < 4; ++u) *(bf16x8*)&Qs[sr][sc + u * 8] = src[u];
  }

  float m_r[4] = {-1e30f, -1e30f, -1e30f, -1e30f};
  float l_r[4] = {0.f, 0.f, 0.f, 0.f};
  f32x4 o[8] = {};
  const int qrow_w = wid * 16;

  for (int kv0 = 0; kv0 <= q0; kv0 += 64) {
    __syncthreads();
    {
      const bf16x8* ksrc = (const bf16x8*)(Kg + (bh + kv0 + sr) * Dh + sc);
      #pragma unroll
      for (int u = 0; u < 4; ++u) *(bf16x8*)&Ks[sr][sc + u * 8] = ksrc[u];
      const bf16x8* vsrc = (const bf16x8*)(Vg + (bh + kv0 + sr) * Dh + sc);
      #pragma unroll
      for (int u = 0; u < 4; ++u) {
        bf16x8 vv = vsrc[u];
        #pragma unroll
        for (int j = 0; j < 8; ++j) Vt[sc + u * 8 + j][sr] = vv[j];
      }
    }
    __syncthreads();

    f32x4 s[4] = {};
    #pragma unroll
    for (int ks = 0; ks < 4; ++ks) {
      bf16x8 aq = *(const bf16x8*)&Qs[qrow_w + l16][ks * 32 + 8 * g];
      #pragma unroll
      for (int nf = 0; nf < 4; ++nf) {
        bf16x8 bk = *(const bf16x8*)&Ks[nf * 16 + l16][ks * 32 + 8 * g];
        s[nf] = mfma16(aq, bk, s[nf]);
      }
    }

    const float scl = 0.08838834764831845f;
    const bool diag = (kv0 == q0);
    float mx[4];
    #pragma unroll
    for (int r = 0; r < 4; ++r) {
      #pragma unroll
      for (int nf = 0; nf < 4; ++nf) {
        float v = s[nf][r] * scl;
        int qrow = qrow_w + 4 * g + r;
        if (diag && (nf * 16 + l16) > qrow) v = -1e30f;
        s[nf][r] = v;
      }
      mx[r] = fmaxf(fmaxf(s[0][r], s[1][r]), fmaxf(s[2][r], s[3][r]));
    }
    #pragma unroll
    for (int off = 1; off < 16; off <<= 1) {
      #pragma unroll
      for (int r = 0; r < 4; ++r) mx[r] = fmaxf(mx[r], __shfl_xor(mx[r], off, 64));
    }

    float al[4], rs[4];
    #pragma unroll
    for (int r = 0; r < 4; ++r) {
      float mn = fmaxf(m_r[r], mx[r]);
      al[r] = __expf(m_r[r] - mn);
      m_r[r] = mn;
      rs[r] = 0.f;
    }
    #pragma unroll
    for (int nf = 0; nf < 4; ++nf)
      #pragma unroll
      for (int r = 0; r < 4; ++r) {
        float p = __expf(s[nf][r] - m_r[r]);
        s[nf][r] = p;
        rs[r] += p;
      }
    #pragma unroll
    for (int off = 1; off < 16; off <<= 1) {
      #pragma unroll
      for (int r = 0; r < 4; ++r) rs[r] += __shfl_xor(rs[r], off, 64);
    }
    #pragma unroll
    for (int r = 0; r < 4; ++r) l_r[r] = l_r[r] * al[r] + rs[r];
    #pragma unroll
    for (int nf2 = 0; nf2 < 8; ++nf2)
      #pragma unroll
      for (int r = 0; r < 4; ++r) o[nf2][r] *= al[r];

    #pragma unroll
    for (int nf = 0; nf < 4; ++nf)
      #pragma unroll
      for (int r = 0; r < 4; ++r)
        Ps[wid][4 * g + r][nf * 16 + l16] = (__bf16)s[nf][r];
    __syncthreads();

    bf16x8 pa0 = *(const bf16x8*)&Ps[wid][l16][8 * g];
    bf16x8 pa1 = *(const bf16x8*)&Ps[wid][l16][32 + 8 * g];
    #pragma unroll
    for (int nf2 = 0; nf2 < 8; ++nf2) {
      bf16x8 vb0 = *(const bf16x8*)&Vt[nf2 * 16 + l16][8 * g];
      bf16x8 vb1 = *(const bf16x8*)&Vt[nf2 * 16 + l16][32 + 8 * g];
      o[nf2] = mfma16(pa0, vb0, o[nf2]);
      o[nf2] = mfma16(pa1, vb1, o[nf2]);
    }
  }

  float inv[4];
  #pragma unroll
  for (int r = 0; r < 4; ++r) inv[r] = 1.0f / l_r[r];
  __bf16* ybase = Yg + ((size_t)(blockIdx.z * Tlen + q0 + qrow_w)) * Cdim
                + blockIdx.y * Dh;
  #pragma unroll
  for (int nf2 = 0; nf2 < 8; ++nf2)
    #pragma unroll
    for (int r = 0; r < 4; ++r)
      ybase[(size_t)(4 * g + r) * Cdim + nf2 * 16 + l16] = (__bf16)(o[nf2][r] * inv[r]);
}

// ---- 3) output GEMM: 256x256, 8 waves, BK=64, counted-vmcnt dbuf -----------
__global__ __launch_bounds__(512, 2) void out_gemm(
    const __bf16* __restrict__ Yb, const __bf16* __restrict__ Wt,
    float* __restrict__ O)
{
  __shared__ struct { __bf16 A[2][256 * 64]; __bf16 B[2][256 * 64]; } sm;

  const int tid = threadIdx.x, lane = tid & 63, wid = tid >> 6;
  const int g = lane >> 4, l16 = lane & 15;
  const int wr = wid >> 2, wc = wid & 3;

  // supertile: 256 blocks = 8 xcd * 2 stl * 16 pos
  const int bid = blockIdx.x;
  const int xcd = bid & 7, idx = bid >> 3;
  const int stl = idx >> 4, pos = idx & 15;
  const int m0 = (xcd * 4 + (pos >> 2)) * 256;
  const int n0 = (stl * 4 + (pos & 3)) * 256;

  const int srow = tid >> 3;
  const int schk = (tid & 7) ^ (srow & 7);
  const __bf16* gA = Yb + (size_t)(m0 + srow) * Cdim + schk * 8;
  const __bf16* gB = Wt + (size_t)(n0 + srow) * Cdim + schk * 8;
  const int ldst = wid * 512;

  f32x4 acc[8][4] = {};
  const int NT = Cdim / 64;

  #pragma unroll
  for (int r = 0; r < 4; ++r) {
    gl16(gA + (size_t)r * 64 * Cdim, &sm.A[0][r * 4096 + ldst]);
    gl16(gB + (size_t)r * 64 * Cdim, &sm.B[0][r * 4096 + ldst]);
  }
  #pragma unroll
  for (int r = 0; r < 4; ++r) {
    gl16(gA + 64 + (size_t)r * 64 * Cdim, &sm.A[1][r * 4096 + ldst]);
    gl16(gB + 64 + (size_t)r * 64 * Cdim, &sm.B[1][r * 4096 + ldst]);
  }

  for (int t = 0; t < NT; ++t) {
    const int p = t & 1;
    if (t < NT - 1) asm volatile("s_waitcnt vmcnt(8)" ::: "memory");
    else            asm volatile("s_waitcnt vmcnt(0)" ::: "memory");
    __builtin_amdgcn_s_barrier();
    __builtin_amdgcn_sched_barrier(0);

    #pragma unroll
    for (int kk = 0; kk < 2; ++kk) {
      bf16x8 a[8], b[4];
      const int ch = (((kk << 2) | g) ^ (l16 & 7)) * 8;
      #pragma unroll
      for (int f = 0; f < 8; ++f)
        a[f] = *(const bf16x8*)&sm.A[p][(wr * 128 + f * 16 + l16) * 64 + ch];
      #pragma unroll
      for (int n = 0; n < 4; ++n)
        b[n] = *(const bf16x8*)&sm.B[p][(wc * 64 + n * 16 + l16) * 64 + ch];
      #pragma unroll
      for (int f = 0; f < 8; ++f)
        #pragma unroll
        for (int n = 0; n < 4; ++n)
          acc[f][n] = mfma16(a[f], b[n], acc[f][n]);
    }

    __builtin_amdgcn_sched_barrier(0);
    asm volatile("s_waitcnt lgkmcnt(0)" ::: "memory");
    __builtin_amdgcn_s_barrier();

    if (t + 2 < NT) {
      const __bf16* pA = gA + (size_t)(t + 2) * 64;
      const __bf16* pB = gB + (size_t)(t + 2) * 64;
      #pragma unroll
      for (int r = 0; r < 4; ++r) {
        gl16(pA + (size_t)r * 64 * Cdim, &sm.A[p][r * 4096 + ldst]);
        gl16(pB + (size_t)r * 64 * Cdim, &sm.B[p][r * 4096 + ldst]);
      }
    }
  }

  #pragma unroll
  for (int f = 0; f < 8; ++f)
    #pragma unroll
    for (int n = 0; n < 4; ++n)
      #pragma unroll
      for (int r = 0; r < 4; ++r)
        O[(size_t)(m0 + wr * 128 + f * 16 + g * 4 + r) * Cdim
          + (n0 + wc * 64 + n * 16 + l16)] = acc[f][n][r];
}

// ---- launch -----------------------------------------------------------------
extern "C" void kernel_launch(void* const* d_in, const int* in_sizes, int n_in,
                              void* d_out, int out_size, void* d_ws, size_t ws_size,
                              hipStream_t stream) {
  const float* x    = (const float*)d_in[0];
  const float* Wqkv = (const float*)d_in[1];
  const float* Wout = (const float*)d_in[2];
  float* out = (float*)d_out;

  float*  cosT   = (float*)d_ws;
  float*  sinT   = cosT + Tlen * 64;
  __bf16* Xb     = (__bf16*)(sinT + Tlen * 64);            // 32MB (reused as Y)
  __bf16* Wqkv_t = Xb + (size_t)Mrows * Cdim;              // 24MB [6144][2048]
  __bf16* Wout_t = Wqkv_t + (size_t)N_QKV * Cdim;          // 8MB  [2048][2048]
  __bf16* Qb     = Wout_t + (size_t)Cdim * Cdim;           // 32MB
  __bf16* Kb     = Qb + (size_t)Bsz * Hn * Tlen * Dh;      // 32MB
  __bf16* Vb     = Kb + (size_t)Bsz * Hn * Tlen * Dh;      // 32MB
  __bf16* Yb     = Xb;

  rope_table_k<<<dim3(512), dim3(256), 0, stream>>>(cosT, sinT);
  f32_to_bf16_k<<<dim3(Mrows * Cdim / (256 * 8)), dim3(256), 0, stream>>>(x, Xb);
  transpose_to_bf16_k<<<dim3(N_QKV / 32, Cdim / 32), dim3(256), 0, stream>>>(
      Wqkv, Wqkv_t, Cdim, N_QKV);
  transpose_to_bf16_k<<<dim3(Cdim / 32, Cdim / 32), dim3(256), 0, stream>>>(
      Wout, Wout_t, Cdim, Cdim);
  qkv_gemm<<<dim3(768), dim3(512), 0, stream>>>(
      Xb, Wqkv_t, Qb, Kb, Vb, cosT, sinT);
  attn_fwd<<<dim3(Tlen / 64, Hn, Bsz), dim3(256), 0, stream>>>(Qb, Kb, Vb, Yb);
  out_gemm<<<dim3(256), dim3(512), 0, stream>>>(Yb, Wout_t, out);
}

// Round 7
// 732.170 us; speedup vs baseline: 2.1471x; 1.1920x over previous
//
#include <hip/hip_runtime.h>
#include <hip/hip_bf16.h>
#include <cmath>

// ---- constants -------------------------------------------------------------
#define Bsz   4
#define Tlen  2048
#define Cdim  2048
#define Hn    16
#define Dh    128
#define N_QKV 6144
#define Mrows 8192          // B*T

typedef __bf16 bf16x8 __attribute__((ext_vector_type(8)));
typedef __bf16 bf16x4 __attribute__((ext_vector_type(4)));
typedef float  f32x4  __attribute__((ext_vector_type(4)));

__device__ __forceinline__ f32x4 mfma16(bf16x8 a, bf16x8 b, f32x4 c) {
  return __builtin_amdgcn_mfma_f32_16x16x32_bf16(a, b, c, 0, 0, 0);
}

__device__ __forceinline__ void gl16(const void* g, void* l) {
  __builtin_amdgcn_global_load_lds(
      (const __attribute__((address_space(1))) void*)g,
      (__attribute__((address_space(3))) void*)l, 16, 0, 0);
}

// ---- 0) RoPE cos/sin table: [T][64] each ----------------------------------
__global__ void rope_table_k(float* __restrict__ cosT, float* __restrict__ sinT) {
  int idx = blockIdx.x * 256 + threadIdx.x;
  int t = idx >> 6, i = idx & 63;
  float invf = __expf(-(float)i * 0.14391156698f);   // 10000^(-i/64)
  float a = (float)t * invf;
  float s, c;
  sincosf(a, &s, &c);
  cosT[idx] = c;
  sinT[idx] = s;
}

// ---- 0b) X fp32 -> bf16 (row-major) ----------------------------------------
__global__ __launch_bounds__(256) void f32_to_bf16_k(
    const float* __restrict__ src, __bf16* __restrict__ dst) {
  size_t i = ((size_t)blockIdx.x * 256 + threadIdx.x) * 8;
  f32x4 a = *(const f32x4*)(src + i);
  f32x4 b = *(const f32x4*)(src + i + 4);
  bf16x8 o;
  o[0] = (__bf16)a[0]; o[1] = (__bf16)a[1]; o[2] = (__bf16)a[2]; o[3] = (__bf16)a[3];
  o[4] = (__bf16)b[0]; o[5] = (__bf16)b[1]; o[6] = (__bf16)b[2]; o[7] = (__bf16)b[3];
  *(bf16x8*)(dst + i) = o;
}

// ---- 0c) W fp32 [K][N] -> bf16 [N][K] (B^T form) ---------------------------
__global__ __launch_bounds__(256) void transpose_to_bf16_k(
    const float* __restrict__ src, __bf16* __restrict__ dst, int K, int N) {
  __shared__ float tile[32][33];
  int n0 = blockIdx.x * 32, k0 = blockIdx.y * 32;
  int tr = threadIdx.x >> 3, tc = (threadIdx.x & 7) * 4;
  f32x4 v = *(const f32x4*)&src[(size_t)(k0 + tr) * N + n0 + tc];
  tile[tr][tc + 0] = v[0]; tile[tr][tc + 1] = v[1];
  tile[tr][tc + 2] = v[2]; tile[tr][tc + 3] = v[3];
  __syncthreads();
  bf16x4 w;
  w[0] = (__bf16)tile[tc + 0][tr];
  w[1] = (__bf16)tile[tc + 1][tr];
  w[2] = (__bf16)tile[tc + 2][tr];
  w[3] = (__bf16)tile[tc + 3][tr];
  *(bf16x4*)&dst[(size_t)(n0 + tr) * K + k0 + tc] = w;
}

// ---- 1) QKV GEMM: 256x256, 8 waves, BK=64, counted-vmcnt dbuf --------------
// Xb [8192][2048] bf16, Wt [6144][2048] bf16 (B^T).
// Q,K RoPE'd -> [B][H][T][D]; V -> TRANSPOSED [B][H][D][T].
__global__ __launch_bounds__(512, 2) void qkv_gemm(
    const __bf16* __restrict__ Xb, const __bf16* __restrict__ Wt,
    __bf16* __restrict__ Qo, __bf16* __restrict__ Ko, __bf16* __restrict__ Vo,
    const float* __restrict__ cosT, const float* __restrict__ sinT)
{
  __shared__ union SM {
    struct { __bf16 A[2][256 * 64]; __bf16 B[2][256 * 64]; } s;  // 128 KB dbuf
    float C[64][265];                                            // epilogue
  } sm;

  const int tid = threadIdx.x, lane = tid & 63, wid = tid >> 6;
  const int g = lane >> 4, l16 = lane & 15;
  const int wr = wid >> 2, wc = wid & 3;       // 2 x 4 wave grid

  // supertile: 768 blocks = 8 xcd * 6 stl * 16 pos; each XCD owns 4 by-rows
  const int bid = blockIdx.x;
  const int xcd = bid & 7, idx = bid >> 3;
  const int stl = idx >> 4, pos = idx & 15;
  const int m0 = (xcd * 4 + (pos >> 2)) * 256;
  const int n0 = (stl * 4 + (pos & 3)) * 256;

  const int srow = tid >> 3;                   // 0..63
  const int schk = (tid & 7) ^ (srow & 7);
  const __bf16* gA = Xb + (size_t)(m0 + srow) * Cdim + schk * 8;
  const __bf16* gB = Wt + (size_t)(n0 + srow) * Cdim + schk * 8;
  const int ldst = wid * 512;

  f32x4 acc[8][4] = {};
  const int NT = Cdim / 64;   // 32 K-tiles

  #pragma unroll
  for (int r = 0; r < 4; ++r) {
    gl16(gA + (size_t)r * 64 * Cdim, &sm.s.A[0][r * 4096 + ldst]);
    gl16(gB + (size_t)r * 64 * Cdim, &sm.s.B[0][r * 4096 + ldst]);
  }
  #pragma unroll
  for (int r = 0; r < 4; ++r) {
    gl16(gA + 64 + (size_t)r * 64 * Cdim, &sm.s.A[1][r * 4096 + ldst]);
    gl16(gB + 64 + (size_t)r * 64 * Cdim, &sm.s.B[1][r * 4096 + ldst]);
  }

  for (int t = 0; t < NT; ++t) {
    const int p = t & 1;
    if (t < NT - 1) asm volatile("s_waitcnt vmcnt(8)" ::: "memory");
    else            asm volatile("s_waitcnt vmcnt(0)" ::: "memory");
    __builtin_amdgcn_s_barrier();
    __builtin_amdgcn_sched_barrier(0);

    #pragma unroll
    for (int kk = 0; kk < 2; ++kk) {
      bf16x8 a[8], b[4];
      const int ch = (((kk << 2) | g) ^ (l16 & 7)) * 8;
      #pragma unroll
      for (int f = 0; f < 8; ++f)
        a[f] = *(const bf16x8*)&sm.s.A[p][(wr * 128 + f * 16 + l16) * 64 + ch];
      #pragma unroll
      for (int n = 0; n < 4; ++n)
        b[n] = *(const bf16x8*)&sm.s.B[p][(wc * 64 + n * 16 + l16) * 64 + ch];
      #pragma unroll
      for (int f = 0; f < 8; ++f)
        #pragma unroll
        for (int n = 0; n < 4; ++n)
          acc[f][n] = mfma16(a[f], b[n], acc[f][n]);
    }

    __builtin_amdgcn_sched_barrier(0);
    asm volatile("s_waitcnt lgkmcnt(0)" ::: "memory");
    __builtin_amdgcn_s_barrier();

    if (t + 2 < NT) {
      const __bf16* pA = gA + (size_t)(t + 2) * 64;
      const __bf16* pB = gB + (size_t)(t + 2) * 64;
      #pragma unroll
      for (int r = 0; r < 4; ++r) {
        gl16(pA + (size_t)r * 64 * Cdim, &sm.s.A[p][r * 4096 + ldst]);
        gl16(pB + (size_t)r * 64 * Cdim, &sm.s.B[p][r * 4096 + ldst]);
      }
    }
  }

  // epilogue: four 64-row rounds through LDS f32
  const int sel = n0 >> 11;             // 0=q 1=k 2=v
  const int h0  = (n0 & 2047) >> 7;     // first of 2 heads in this tile
  const int erow = tid >> 3, q = tid & 7;
  const int dlo = (q & 3) * 16;
  const int clo = (q >> 2) * 128 + dlo;
  const int vcol = tid >> 1, vth = tid & 1;      // V^T path mapping

  #pragma unroll
  for (int rh = 0; rh < 4; ++rh) {
    if (wr == (rh >> 1)) {
      const int fb = (rh & 1) * 4;
      #pragma unroll
      for (int f2 = 0; f2 < 4; ++f2)
        #pragma unroll
        for (int n = 0; n < 4; ++n)
          #pragma unroll
          for (int r = 0; r < 4; ++r)
            sm.C[f2 * 16 + g * 4 + r][wc * 64 + n * 16 + l16] = acc[fb + f2][n][r];
    }
    __syncthreads();
    if (sel == 2) {
      // V^T write: thread owns (head', d) column, writes 32 t-contiguous vals
      const int hh = h0 + (vcol >> 7), d = vcol & 127;
      const int mb = m0 + rh * 64 + vth * 32;
      const int b_ = mb >> 11, tt = mb & 2047;
      __bf16* outp = Vo + (((size_t)(b_ * Hn + hh)) * Dh + d) * Tlen + tt;
      bf16x8 w[4];
      #pragma unroll
      for (int i = 0; i < 32; ++i)
        w[i >> 3][i & 7] = (__bf16)sm.C[vth * 32 + i][vcol];
      #pragma unroll
      for (int k = 0; k < 4; ++k) *(bf16x8*)&outp[k * 8] = w[k];
    } else {
      __bf16* dst = (sel == 0) ? Qo : Ko;
      const int m = m0 + rh * 64 + erow;
      const int b_ = m >> 11, t = m & 2047;
      __bf16* out = dst + (((size_t)(b_ * Hn + h0 + (q >> 2))) * Tlen + t) * Dh + dlo;
      const float* cb = cosT + t * 64 + dlo;
      const float* sb = sinT + t * 64 + dlo;
      bf16x8 o1[2], o2[2];
      #pragma unroll
      for (int i = 0; i < 16; ++i) {
        float v1 = sm.C[erow][clo + i];
        float v2 = sm.C[erow][clo + i + 64];
        float cs = cb[i], sn = sb[i];
        float r1 = v1 * cs - v2 * sn;
        float r2 = v2 * cs + v1 * sn;
        o1[i >> 3][i & 7] = (__bf16)r1;
        o2[i >> 3][i & 7] = (__bf16)r2;
      }
      *(bf16x8*)&out[0]  = o1[0];
      *(bf16x8*)&out[8]  = o1[1];
      *(bf16x8*)&out[64] = o2[0];
      *(bf16x8*)&out[72] = o2[1];
    }
    __syncthreads();
  }
}

// ---- 2) Flash attention (causal), dbuf gl16 staging, reg-Q -----------------
// Q,K bf16 [B][H][T][D]; V bf16 [B][H][D][T] (pre-transposed); Y -> [B][T][C].
__global__ __launch_bounds__(256, 2) void attn_fwd(
    const __bf16* __restrict__ Qg, const __bf16* __restrict__ Kg,
    const __bf16* __restrict__ Vtg, __bf16* __restrict__ Yg)
{
  __shared__ __bf16 Ks[2][64 * 128];   // XOR-chunk swizzled
  __shared__ __bf16 Vt[2][128 * 64];   // V^T tile, swizzled
  __shared__ __bf16 Ps[4][16][72];     // per-wave P

  const int tid = threadIdx.x, lane = tid & 63, wid = tid >> 6;
  const int g = lane >> 4, l16 = lane & 15;
  const int qt = gridDim.x - 1 - blockIdx.x;     // heavy blocks first
  const int q0 = qt * 64;
  const size_t bh = (size_t)blockIdx.z * Hn + blockIdx.y;
  const __bf16* Kbase = Kg + bh * ((size_t)Tlen * Dh);
  const __bf16* Vbase = Vtg + bh * ((size_t)Dh * Tlen);

  // Q fragments in registers (wave's 16 q-rows)
  bf16x8 aq[4];
  {
    const __bf16* qrow = Qg + (bh * Tlen + q0 + wid * 16 + l16) * Dh;
    #pragma unroll
    for (int ks = 0; ks < 4; ++ks)
      aq[ks] = *(const bf16x8*)(qrow + ks * 32 + 8 * g);
  }

  float m_r[4], l_r[4];
  #pragma unroll
  for (int r = 0; r < 4; ++r) { m_r[r] = -1e30f; l_r[r] = 0.f; }
  f32x4 o[8] = {};

  const int NKV = qt + 1;

  // staging: K rows wid*16..+15 (16 chunks/row), V rows wid*32..+31 (8 chunks)
  const int krow = lane >> 4, kchk = lane & 15;
  const int vrow = lane >> 3, vchk = lane & 7;

#define STAGE_KV(kv0_, buf_)                                                    \
  {                                                                             \
    _Pragma("unroll")                                                           \
    for (int rr = 0; rr < 4; ++rr) {                                            \
      const int row = wid * 16 + rr * 4 + krow;                                 \
      const int sc = kchk ^ (row & 7);                                          \
      gl16(Kbase + (size_t)((kv0_) + row) * Dh + sc * 8,                        \
           &Ks[buf_][(wid * 16 + rr * 4) * 128]);                               \
    }                                                                           \
    _Pragma("unroll")                                                           \
    for (int rr = 0; rr < 4; ++rr) {                                            \
      const int row = wid * 32 + rr * 8 + vrow;                                 \
      const int sc = vchk ^ (row & 7);                                          \
      gl16(Vbase + (size_t)row * Tlen + (kv0_) + sc * 8,                        \
           &Vt[buf_][(wid * 32 + rr * 8) * 64]);                                \
    }                                                                           \
  }

  STAGE_KV(0, 0);

  for (int it = 0; it < NKV; ++it) {
    const int p = it & 1;
    if (it + 1 < NKV) {
      STAGE_KV((it + 1) * 64, (it + 1) & 1);
      asm volatile("s_waitcnt vmcnt(8)" ::: "memory");
    } else {
      asm volatile("s_waitcnt vmcnt(0)" ::: "memory");
    }
    __builtin_amdgcn_s_barrier();
    __builtin_amdgcn_sched_barrier(0);

    // S = Q K^T (16 x 64), C-layout: row 4g+r, col(kv) nf*16+l16
    f32x4 s[4] = {};
    #pragma unroll
    for (int ks = 0; ks < 4; ++ks) {
      const int ch = ((4 * ks + g) ^ (l16 & 7)) * 8;
      #pragma unroll
      for (int nf = 0; nf < 4; ++nf) {
        bf16x8 bk = *(const bf16x8*)&Ks[p][(nf * 16 + l16) * 128 + ch];
        s[nf] = mfma16(aq[ks], bk, s[nf]);
      }
    }

    const float scl = 0.08838834764831845f;   // 1/sqrt(128)
    #pragma unroll
    for (int nf = 0; nf < 4; ++nf)
      #pragma unroll
      for (int r = 0; r < 4; ++r) s[nf][r] *= scl;
    if ((it + 1) * 64 > q0) {                 // diagonal tile: mask
      #pragma unroll
      for (int nf = 0; nf < 4; ++nf) {
        const int col = nf * 16 + l16;
        #pragma unroll
        for (int r = 0; r < 4; ++r)
          if (col > wid * 16 + 4 * g + r) s[nf][r] = -1e30f;
      }
    }

    float mx[4];
    #pragma unroll
    for (int r = 0; r < 4; ++r)
      mx[r] = fmaxf(fmaxf(s[0][r], s[1][r]), fmaxf(s[2][r], s[3][r]));
    #pragma unroll
    for (int off = 1; off < 16; off <<= 1)
      #pragma unroll
      for (int r = 0; r < 4; ++r)
        mx[r] = fmaxf(mx[r], __shfl_xor(mx[r], off, 64));

    int grow = 0;
    #pragma unroll
    for (int r = 0; r < 4; ++r) grow |= (mx[r] > m_r[r]) ? 1 : 0;
    if (__any(grow)) {                        // exact skip when no new max
      #pragma unroll
      for (int r = 0; r < 4; ++r) {
        const float mn = fmaxf(m_r[r], mx[r]);
        const float al = __expf(m_r[r] - mn);
        m_r[r] = mn;
        l_r[r] *= al;
        #pragma unroll
        for (int n2 = 0; n2 < 8; ++n2) o[n2][r] *= al;
      }
    }

    float rs[4] = {0.f, 0.f, 0.f, 0.f};
    #pragma unroll
    for (int nf = 0; nf < 4; ++nf)
      #pragma unroll
      for (int r = 0; r < 4; ++r) {
        const float pv = __expf(s[nf][r] - m_r[r]);
        s[nf][r] = pv;
        rs[r] += pv;
      }
    #pragma unroll
    for (int off = 1; off < 16; off <<= 1)
      #pragma unroll
      for (int r = 0; r < 4; ++r) rs[r] += __shfl_xor(rs[r], off, 64);
    #pragma unroll
    for (int r = 0; r < 4; ++r) l_r[r] += rs[r];

    // P -> per-wave LDS (C-layout -> A-fragment layout)
    #pragma unroll
    for (int nf = 0; nf < 4; ++nf)
      #pragma unroll
      for (int r = 0; r < 4; ++r)
        Ps[wid][4 * g + r][nf * 16 + l16] = (__bf16)s[nf][r];
    asm volatile("s_waitcnt lgkmcnt(0)" ::: "memory");
    __builtin_amdgcn_sched_barrier(0);

    bf16x8 pa0 = *(const bf16x8*)&Ps[wid][l16][8 * g];
    bf16x8 pa1 = *(const bf16x8*)&Ps[wid][l16][32 + 8 * g];
    const int c0 = (g ^ (l16 & 7)) * 8;
    const int c1 = ((4 + g) ^ (l16 & 7)) * 8;
    #pragma unroll
    for (int n2 = 0; n2 < 8; ++n2) {
      bf16x8 vb0 = *(const bf16x8*)&Vt[p][(n2 * 16 + l16) * 64 + c0];
      bf16x8 vb1 = *(const bf16x8*)&Vt[p][(n2 * 16 + l16) * 64 + c1];
      o[n2] = mfma16(pa0, vb0, o[n2]);
      o[n2] = mfma16(pa1, vb1, o[n2]);
    }

    asm volatile("s_waitcnt lgkmcnt(0)" ::: "memory");
    __builtin_amdgcn_sched_barrier(0);
    __builtin_amdgcn_s_barrier();
  }
#undef STAGE_KV

  float inv[4];
  #pragma unroll
  for (int r = 0; r < 4; ++r) inv[r] = 1.0f / l_r[r];
  __bf16* ybase = Yg + ((size_t)(blockIdx.z * Tlen + q0 + wid * 16)) * Cdim
                + blockIdx.y * Dh;
  #pragma unroll
  for (int n2 = 0; n2 < 8; ++n2)
    #pragma unroll
    for (int r = 0; r < 4; ++r)
      ybase[(size_t)(4 * g + r) * Cdim + n2 * 16 + l16] = (__bf16)(o[n2][r] * inv[r]);
}

// ---- 3) output GEMM: 256x256, 8 waves, BK=64, counted-vmcnt dbuf -----------
__global__ __launch_bounds__(512, 2) void out_gemm(
    const __bf16* __restrict__ Yb, const __bf16* __restrict__ Wt,
    float* __restrict__ O)
{
  __shared__ struct { __bf16 A[2][256 * 64]; __bf16 B[2][256 * 64]; } sm;

  const int tid = threadIdx.x, lane = tid & 63, wid = tid >> 6;
  const int g = lane >> 4, l16 = lane & 15;
  const int wr = wid >> 2, wc = wid & 3;

  const int bid = blockIdx.x;
  const int xcd = bid & 7, idx = bid >> 3;
  const int stl = idx >> 4, pos = idx & 15;
  const int m0 = (xcd * 4 + (pos >> 2)) * 256;
  const int n0 = (stl * 4 + (pos & 3)) * 256;

  const int srow = tid >> 3;
  const int schk = (tid & 7) ^ (srow & 7);
  const __bf16* gA = Yb + (size_t)(m0 + srow) * Cdim + schk * 8;
  const __bf16* gB = Wt + (size_t)(n0 + srow) * Cdim + schk * 8;
  const int ldst = wid * 512;

  f32x4 acc[8][4] = {};
  const int NT = Cdim / 64;

  #pragma unroll
  for (int r = 0; r < 4; ++r) {
    gl16(gA + (size_t)r * 64 * Cdim, &sm.A[0][r * 4096 + ldst]);
    gl16(gB + (size_t)r * 64 * Cdim, &sm.B[0][r * 4096 + ldst]);
  }
  #pragma unroll
  for (int r = 0; r < 4; ++r) {
    gl16(gA + 64 + (size_t)r * 64 * Cdim, &sm.A[1][r * 4096 + ldst]);
    gl16(gB + 64 + (size_t)r * 64 * Cdim, &sm.B[1][r * 4096 + ldst]);
  }

  for (int t = 0; t < NT; ++t) {
    const int p = t & 1;
    if (t < NT - 1) asm volatile("s_waitcnt vmcnt(8)" ::: "memory");
    else            asm volatile("s_waitcnt vmcnt(0)" ::: "memory");
    __builtin_amdgcn_s_barrier();
    __builtin_amdgcn_sched_barrier(0);

    #pragma unroll
    for (int kk = 0; kk < 2; ++kk) {
      bf16x8 a[8], b[4];
      const int ch = (((kk << 2) | g) ^ (l16 & 7)) * 8;
      #pragma unroll
      for (int f = 0; f < 8; ++f)
        a[f] = *(const bf16x8*)&sm.A[p][(wr * 128 + f * 16 + l16) * 64 + ch];
      #pragma unroll
      for (int n = 0; n < 4; ++n)
        b[n] = *(const bf16x8*)&sm.B[p][(wc * 64 + n * 16 + l16) * 64 + ch];
      #pragma unroll
      for (int f = 0; f < 8; ++f)
        #pragma unroll
        for (int n = 0; n < 4; ++n)
          acc[f][n] = mfma16(a[f], b[n], acc[f][n]);
    }

    __builtin_amdgcn_sched_barrier(0);
    asm volatile("s_waitcnt lgkmcnt(0)" ::: "memory");
    __builtin_amdgcn_s_barrier();

    if (t + 2 < NT) {
      const __bf16* pA = gA + (size_t)(t + 2) * 64;
      const __bf16* pB = gB + (size_t)(t + 2) * 64;
      #pragma unroll
      for (int r = 0; r < 4; ++r) {
        gl16(pA + (size_t)r * 64 * Cdim, &sm.A[p][r * 4096 + ldst]);
        gl16(pB + (size_t)r * 64 * Cdim, &sm.B[p][r * 4096 + ldst]);
      }
    }
  }

  #pragma unroll
  for (int f = 0; f < 8; ++f)
    #pragma unroll
    for (int n = 0; n < 4; ++n)
      #pragma unroll
      for (int r = 0; r < 4; ++r)
        O[(size_t)(m0 + wr * 128 + f * 16 + g * 4 + r) * Cdim
          + (n0 + wc * 64 + n * 16 + l16)] = acc[f][n][r];
}

// ---- launch -----------------------------------------------------------------
extern "C" void kernel_launch(void* const* d_in, const int* in_sizes, int n_in,
                              void* d_out, int out_size, void* d_ws, size_t ws_size,
                              hipStream_t stream) {
  const float* x    = (const float*)d_in[0];
  const float* Wqkv = (const float*)d_in[1];
  const float* Wout = (const float*)d_in[2];
  float* out = (float*)d_out;

  float*  cosT   = (float*)d_ws;
  float*  sinT   = cosT + Tlen * 64;
  __bf16* Xb     = (__bf16*)(sinT + Tlen * 64);            // 32MB (reused as Y)
  __bf16* Wqkv_t = Xb + (size_t)Mrows * Cdim;              // 24MB [6144][2048]
  __bf16* Wout_t = Wqkv_t + (size_t)N_QKV * Cdim;          // 8MB  [2048][2048]
  __bf16* Qb     = Wout_t + (size_t)Cdim * Cdim;           // 32MB [B][H][T][D]
  __bf16* Kb     = Qb + (size_t)Bsz * Hn * Tlen * Dh;      // 32MB [B][H][T][D]
  __bf16* Vb     = Kb + (size_t)Bsz * Hn * Tlen * Dh;      // 32MB [B][H][D][T]
  __bf16* Yb     = Xb;

  rope_table_k<<<dim3(512), dim3(256), 0, stream>>>(cosT, sinT);
  f32_to_bf16_k<<<dim3(Mrows * Cdim / (256 * 8)), dim3(256), 0, stream>>>(x, Xb);
  transpose_to_bf16_k<<<dim3(N_QKV / 32, Cdim / 32), dim3(256), 0, stream>>>(
      Wqkv, Wqkv_t, Cdim, N_QKV);
  transpose_to_bf16_k<<<dim3(Cdim / 32, Cdim / 32), dim3(256), 0, stream>>>(
      Wout, Wout_t, Cdim, Cdim);
  qkv_gemm<<<dim3(768), dim3(512), 0, stream>>>(
      Xb, Wqkv_t, Qb, Kb, Vb, cosT, sinT);
  attn_fwd<<<dim3(Tlen / 64, Hn, Bsz), dim3(256), 0, stream>>>(Qb, Kb, Vb, Yb);
  out_gemm<<<dim3(256), dim3(512), 0, stream>>>(Yb, Wout_t, out);
}

// Round 9
// 669.956 us; speedup vs baseline: 2.3464x; 1.0929x over previous
//
#include <hip/hip_runtime.h>
#include <hip/hip_bf16.h>
#include <cmath>

// ---- constants -------------------------------------------------------------
#define Bsz   4
#define Tlen  2048
#define Cdim  2048
#define Hn    16
#define Dh    128
#define N_QKV 6144
#define Mrows 8192          // B*T

typedef __bf16 bf16x8 __attribute__((ext_vector_type(8)));
typedef __bf16 bf16x4 __attribute__((ext_vector_type(4)));
typedef float  f32x4  __attribute__((ext_vector_type(4)));
typedef uint32_t u32x2 __attribute__((ext_vector_type(2)));

__device__ __forceinline__ f32x4 mfma16(bf16x8 a, bf16x8 b, f32x4 c) {
  return __builtin_amdgcn_mfma_f32_16x16x32_bf16(a, b, c, 0, 0, 0);
}

__device__ __forceinline__ void gl16(const void* g, void* l) {
  __builtin_amdgcn_global_load_lds(
      (const __attribute__((address_space(1))) void*)g,
      (__attribute__((address_space(3))) void*)l, 16, 0, 0);
}

__device__ __forceinline__ uint32_t pack_bf16(float lo, float hi) {
  union { __bf16 h; unsigned short u; } a, b;
  a.h = (__bf16)lo; b.h = (__bf16)hi;
  return (uint32_t)a.u | ((uint32_t)b.u << 16);
}

// ---- 0) RoPE cos/sin table: [T][64] each ----------------------------------
__global__ void rope_table_k(float* __restrict__ cosT, float* __restrict__ sinT) {
  int idx = blockIdx.x * 256 + threadIdx.x;
  int t = idx >> 6, i = idx & 63;
  float invf = __expf(-(float)i * 0.14391156698f);   // 10000^(-i/64)
  float a = (float)t * invf;
  float s, c;
  sincosf(a, &s, &c);
  cosT[idx] = c;
  sinT[idx] = s;
}

// ---- 0b) X fp32 -> bf16 (row-major) ----------------------------------------
__global__ __launch_bounds__(256) void f32_to_bf16_k(
    const float* __restrict__ src, __bf16* __restrict__ dst) {
  size_t i = ((size_t)blockIdx.x * 256 + threadIdx.x) * 8;
  f32x4 a = *(const f32x4*)(src + i);
  f32x4 b = *(const f32x4*)(src + i + 4);
  bf16x8 o;
  o[0] = (__bf16)a[0]; o[1] = (__bf16)a[1]; o[2] = (__bf16)a[2]; o[3] = (__bf16)a[3];
  o[4] = (__bf16)b[0]; o[5] = (__bf16)b[1]; o[6] = (__bf16)b[2]; o[7] = (__bf16)b[3];
  *(bf16x8*)(dst + i) = o;
}

// ---- 0c) W fp32 [K][N] -> bf16 [N][K] (B^T form) ---------------------------
__global__ __launch_bounds__(256) void transpose_to_bf16_k(
    const float* __restrict__ src, __bf16* __restrict__ dst, int K, int N) {
  __shared__ float tile[32][33];
  int n0 = blockIdx.x * 32, k0 = blockIdx.y * 32;
  int tr = threadIdx.x >> 3, tc = (threadIdx.x & 7) * 4;
  f32x4 v = *(const f32x4*)&src[(size_t)(k0 + tr) * N + n0 + tc];
  tile[tr][tc + 0] = v[0]; tile[tr][tc + 1] = v[1];
  tile[tr][tc + 2] = v[2]; tile[tr][tc + 3] = v[3];
  __syncthreads();
  bf16x4 w;
  w[0] = (__bf16)tile[tc + 0][tr];
  w[1] = (__bf16)tile[tc + 1][tr];
  w[2] = (__bf16)tile[tc + 2][tr];
  w[3] = (__bf16)tile[tc + 3][tr];
  *(bf16x4*)&dst[(size_t)(n0 + tr) * K + k0 + tc] = w;
}

// ---- 1) QKV GEMM: 256x256, 8 waves, BK=64, counted-vmcnt dbuf --------------
// Xb [8192][2048] bf16, Wt [6144][2048] bf16 (B^T).
// Q,K RoPE'd -> [B][H][T][D]; V -> TRANSPOSED [B][H][D][T].
__global__ __launch_bounds__(512, 2) void qkv_gemm(
    const __bf16* __restrict__ Xb, const __bf16* __restrict__ Wt,
    __bf16* __restrict__ Qo, __bf16* __restrict__ Ko, __bf16* __restrict__ Vo,
    const float* __restrict__ cosT, const float* __restrict__ sinT)
{
  __shared__ union SM {
    struct { __bf16 A[2][256 * 64]; __bf16 B[2][256 * 64]; } s;  // 128 KB dbuf
    float C[64][265];                                            // epilogue
  } sm;

  const int tid = threadIdx.x, lane = tid & 63, wid = tid >> 6;
  const int g = lane >> 4, l16 = lane & 15;
  const int wr = wid >> 2, wc = wid & 3;       // 2 x 4 wave grid

  // supertile: 768 blocks = 8 xcd * 6 stl * 16 pos; each XCD owns 4 by-rows
  const int bid = blockIdx.x;
  const int xcd = bid & 7, idx = bid >> 3;
  const int stl = idx >> 4, pos = idx & 15;
  const int m0 = (xcd * 4 + (pos >> 2)) * 256;
  const int n0 = (stl * 4 + (pos & 3)) * 256;

  const int srow = tid >> 3;                   // 0..63
  const int schk = (tid & 7) ^ (srow & 7);
  const __bf16* gA = Xb + (size_t)(m0 + srow) * Cdim + schk * 8;
  const __bf16* gB = Wt + (size_t)(n0 + srow) * Cdim + schk * 8;
  const int ldst = wid * 512;

  f32x4 acc[8][4] = {};
  const int NT = Cdim / 64;   // 32 K-tiles

  #pragma unroll
  for (int r = 0; r < 4; ++r) {
    gl16(gA + (size_t)r * 64 * Cdim, &sm.s.A[0][r * 4096 + ldst]);
    gl16(gB + (size_t)r * 64 * Cdim, &sm.s.B[0][r * 4096 + ldst]);
  }
  #pragma unroll
  for (int r = 0; r < 4; ++r) {
    gl16(gA + 64 + (size_t)r * 64 * Cdim, &sm.s.A[1][r * 4096 + ldst]);
    gl16(gB + 64 + (size_t)r * 64 * Cdim, &sm.s.B[1][r * 4096 + ldst]);
  }

  for (int t = 0; t < NT; ++t) {
    const int p = t & 1;
    if (t < NT - 1) asm volatile("s_waitcnt vmcnt(8)" ::: "memory");
    else            asm volatile("s_waitcnt vmcnt(0)" ::: "memory");
    __builtin_amdgcn_s_barrier();
    __builtin_amdgcn_sched_barrier(0);

    #pragma unroll
    for (int kk = 0; kk < 2; ++kk) {
      bf16x8 a[8], b[4];
      const int ch = (((kk << 2) | g) ^ (l16 & 7)) * 8;
      #pragma unroll
      for (int f = 0; f < 8; ++f)
        a[f] = *(const bf16x8*)&sm.s.A[p][(wr * 128 + f * 16 + l16) * 64 + ch];
      #pragma unroll
      for (int n = 0; n < 4; ++n)
        b[n] = *(const bf16x8*)&sm.s.B[p][(wc * 64 + n * 16 + l16) * 64 + ch];
      #pragma unroll
      for (int f = 0; f < 8; ++f)
        #pragma unroll
        for (int n = 0; n < 4; ++n)
          acc[f][n] = mfma16(a[f], b[n], acc[f][n]);
    }

    __builtin_amdgcn_sched_barrier(0);
    asm volatile("s_waitcnt lgkmcnt(0)" ::: "memory");
    __builtin_amdgcn_s_barrier();

    if (t + 2 < NT) {
      const __bf16* pA = gA + (size_t)(t + 2) * 64;
      const __bf16* pB = gB + (size_t)(t + 2) * 64;
      #pragma unroll
      for (int r = 0; r < 4; ++r) {
        gl16(pA + (size_t)r * 64 * Cdim, &sm.s.A[p][r * 4096 + ldst]);
        gl16(pB + (size_t)r * 64 * Cdim, &sm.s.B[p][r * 4096 + ldst]);
      }
    }
  }

  // epilogue: four 64-row rounds through LDS f32
  const int sel = n0 >> 11;             // 0=q 1=k 2=v
  const int h0  = (n0 & 2047) >> 7;     // first of 2 heads in this tile
  const int erow = tid >> 3, q = tid & 7;
  const int dlo = (q & 3) * 16;
  const int clo = (q >> 2) * 128 + dlo;
  const int vcol = tid >> 1, vth = tid & 1;      // V^T path mapping

  #pragma unroll
  for (int rh = 0; rh < 4; ++rh) {
    if (wr == (rh >> 1)) {
      const int fb = (rh & 1) * 4;
      #pragma unroll
      for (int f2 = 0; f2 < 4; ++f2)
        #pragma unroll
        for (int n = 0; n < 4; ++n)
          #pragma unroll
          for (int r = 0; r < 4; ++r)
            sm.C[f2 * 16 + g * 4 + r][wc * 64 + n * 16 + l16] = acc[fb + f2][n][r];
    }
    __syncthreads();
    if (sel == 2) {
      // V^T write: thread owns (head', d) column, writes 32 t-contiguous vals
      const int hh = h0 + (vcol >> 7), d = vcol & 127;
      const int mb = m0 + rh * 64 + vth * 32;
      const int b_ = mb >> 11, tt = mb & 2047;
      __bf16* outp = Vo + (((size_t)(b_ * Hn + hh)) * Dh + d) * Tlen + tt;
      bf16x8 w[4];
      #pragma unroll
      for (int i = 0; i < 32; ++i)
        w[i >> 3][i & 7] = (__bf16)sm.C[vth * 32 + i][vcol];
      #pragma unroll
      for (int k = 0; k < 4; ++k) *(bf16x8*)&outp[k * 8] = w[k];
    } else {
      __bf16* dst = (sel == 0) ? Qo : Ko;
      const int m = m0 + rh * 64 + erow;
      const int b_ = m >> 11, t = m & 2047;
      __bf16* out = dst + (((size_t)(b_ * Hn + h0 + (q >> 2))) * Tlen + t) * Dh + dlo;
      const float* cb = cosT + t * 64 + dlo;
      const float* sb = sinT + t * 64 + dlo;
      bf16x8 o1[2], o2[2];
      #pragma unroll
      for (int i = 0; i < 16; ++i) {
        float v1 = sm.C[erow][clo + i];
        float v2 = sm.C[erow][clo + i + 64];
        float cs = cb[i], sn = sb[i];
        float r1 = v1 * cs - v2 * sn;
        float r2 = v2 * cs + v1 * sn;
        o1[i >> 3][i & 7] = (__bf16)r1;
        o2[i >> 3][i & 7] = (__bf16)r2;
      }
      *(bf16x8*)&out[0]  = o1[0];
      *(bf16x8*)&out[8]  = o1[1];
      *(bf16x8*)&out[64] = o2[0];
      *(bf16x8*)&out[72] = o2[1];
    }
    __syncthreads();
  }
}

// ---- 2) Flash attention (causal), swapped QK^T, in-register softmax --------
// Q,K bf16 [B][H][T][D]; V bf16 [B][H][D][T] (pre-transposed); Y -> [B][T][C].
__global__ __launch_bounds__(256, 2) void attn_fwd(
    const __bf16* __restrict__ Qg, const __bf16* __restrict__ Kg,
    const __bf16* __restrict__ Vtg, __bf16* __restrict__ Yg)
{
  __shared__ __bf16 Ks[2][64 * 128];       // XOR-chunk swizzled
  __shared__ __bf16 Vt[2][128 * 64];       // V^T tile, swizzled
  __shared__ uint32_t Ps2[4][16 * 34 + 2]; // per-wave P in B-frag layout (u32 pairs)

  const int tid = threadIdx.x, lane = tid & 63, wid = tid >> 6;
  const int g = lane >> 4, l16 = lane & 15;
  const int qt = gridDim.x - 1 - blockIdx.x;     // heavy blocks first
  const int q0 = qt * 64;
  const size_t bh = (size_t)blockIdx.z * Hn + blockIdx.y;
  const __bf16* Kbase = Kg + bh * ((size_t)Tlen * Dh);
  const __bf16* Vbase = Vtg + bh * ((size_t)Dh * Tlen);

  const int q_glob = q0 + wid * 16 + l16;        // this lane's q row

  // Q fragments in registers: B-operand, B[k=8g+j][col=q=l16]
  bf16x8 aq[4];
  {
    const __bf16* qrow = Qg + (bh * Tlen + q_glob) * Dh;
    #pragma unroll
    for (int ks = 0; ks < 4; ++ks)
      aq[ks] = *(const bf16x8*)(qrow + ks * 32 + 8 * g);
  }

  float m_r = -1e30f, l_r = 0.f;
  f32x4 o[8] = {};                               // O^T: d = 16n2+4g+r, q = l16
  const float k_e = 0.08838834764831845f * 1.4426950408889634f; // scl*log2(e)

  const int NKV = qt + 1;

  const int krow = lane >> 4, kchk = lane & 15;
  const int vrow = lane >> 3, vchk = lane & 7;

#define STAGE_KV(kv0_, buf_)                                                    \
  {                                                                             \
    _Pragma("unroll")                                                           \
    for (int rr = 0; rr < 4; ++rr) {                                            \
      const int row = wid * 16 + rr * 4 + krow;                                 \
      const int sc = kchk ^ (row & 7);                                          \
      gl16(Kbase + (size_t)((kv0_) + row) * Dh + sc * 8,                        \
           &Ks[buf_][(wid * 16 + rr * 4) * 128]);                               \
    }                                                                           \
    _Pragma("unroll")                                                           \
    for (int rr = 0; rr < 4; ++rr) {                                            \
      const int row = wid * 32 + rr * 8 + vrow;                                 \
      const int sc = vchk ^ (row & 7);                                          \
      gl16(Vbase + (size_t)row * Tlen + (kv0_) + sc * 8,                        \
           &Vt[buf_][(wid * 32 + rr * 8) * 64]);                                \
    }                                                                           \
  }

  STAGE_KV(0, 0);

  for (int it = 0; it < NKV; ++it) {
    const int p = it & 1;
    if (it + 1 < NKV) {
      STAGE_KV((it + 1) * 64, (it + 1) & 1);
      asm volatile("s_waitcnt vmcnt(8)" ::: "memory");
    } else {
      asm volatile("s_waitcnt vmcnt(0)" ::: "memory");
    }
    __builtin_amdgcn_s_barrier();
    __builtin_amdgcn_sched_barrier(0);

    // S^T = K Q^T : s[nf][r] = S[kv = it*64 + nf*16 + 4g + r][q = l16]
    f32x4 s[4] = {};
    __builtin_amdgcn_s_setprio(1);
    #pragma unroll
    for (int ks = 0; ks < 4; ++ks) {
      const int ch = ((4 * ks + g) ^ (l16 & 7)) * 8;
      #pragma unroll
      for (int nf = 0; nf < 4; ++nf) {
        bf16x8 bk = *(const bf16x8*)&Ks[p][(nf * 16 + l16) * 128 + ch];
        s[nf] = mfma16(bk, aq[ks], s[nf]);     // swapped: A=K, B=Q^T
      }
    }
    __builtin_amdgcn_s_setprio(0);

    if (it == qt) {                              // diagonal tile: causal mask
      const int kvb = it * 64 + 4 * g;
      #pragma unroll
      for (int nf = 0; nf < 4; ++nf)
        #pragma unroll
        for (int r = 0; r < 4; ++r)
          if (kvb + nf * 16 + r > q_glob) s[nf][r] = -1e30f;
    }

    // per-lane max over 16 kv values + 2-stage cross-g reduce
    float mx = s[0][0];
    #pragma unroll
    for (int nf = 0; nf < 4; ++nf)
      #pragma unroll
      for (int r = 0; r < 4; ++r) mx = fmaxf(mx, s[nf][r]);
    mx = fmaxf(mx, __shfl_xor(mx, 16, 64));
    mx = fmaxf(mx, __shfl_xor(mx, 32, 64));

    if (__any(mx > m_r)) {                       // exact skip when no new max
      const float mn = fmaxf(m_r, mx);
      const float al = exp2f((m_r - mn) * k_e);
      m_r = mn;
      l_r *= al;
      #pragma unroll
      for (int n2 = 0; n2 < 8; ++n2)
        #pragma unroll
        for (int r = 0; r < 4; ++r) o[n2][r] *= al;
    }

    const float mk = -m_r * k_e;
    float rs = 0.f;
    #pragma unroll
    for (int nf = 0; nf < 4; ++nf)
      #pragma unroll
      for (int r = 0; r < 4; ++r) {
        const float pv = exp2f(fmaf(s[nf][r], k_e, mk));
        s[nf][r] = pv;
        rs += pv;
      }
    rs += __shfl_xor(rs, 16, 64);
    rs += __shfl_xor(rs, 32, 64);
    l_r += rs;

    // P -> B-fragment layout via per-wave LDS: row q=l16, u32 col = kv/2
    #pragma unroll
    for (int nf = 0; nf < 4; ++nf) {
      u32x2 wv;
      wv.x = pack_bf16(s[nf][0], s[nf][1]);
      wv.y = pack_bf16(s[nf][2], s[nf][3]);
      *(u32x2*)&Ps2[wid][l16 * 34 + nf * 8 + 2 * g] = wv;   // kv = 16nf+4g+0..3
    }
    asm volatile("s_waitcnt lgkmcnt(0)" ::: "memory");
    __builtin_amdgcn_sched_barrier(0);

    union { u32x2 h[2]; bf16x8 v; } pb0, pb1;
    pb0.h[0] = *(const u32x2*)&Ps2[wid][l16 * 34 + 4 * g];
    pb0.h[1] = *(const u32x2*)&Ps2[wid][l16 * 34 + 4 * g + 2];
    pb1.h[0] = *(const u32x2*)&Ps2[wid][l16 * 34 + 16 + 4 * g];
    pb1.h[1] = *(const u32x2*)&Ps2[wid][l16 * 34 + 16 + 4 * g + 2];

    const int c0 = (g ^ (l16 & 7)) * 8;
    const int c1 = ((4 + g) ^ (l16 & 7)) * 8;
    __builtin_amdgcn_s_setprio(1);
    #pragma unroll
    for (int n2 = 0; n2 < 8; ++n2) {
      bf16x8 vb0 = *(const bf16x8*)&Vt[p][(n2 * 16 + l16) * 64 + c0];
      bf16x8 vb1 = *(const bf16x8*)&Vt[p][(n2 * 16 + l16) * 64 + c1];
      o[n2] = mfma16(vb0, pb0.v, o[n2]);         // O^T = V^T P
      o[n2] = mfma16(vb1, pb1.v, o[n2]);
    }
    __builtin_amdgcn_s_setprio(0);

    asm volatile("s_waitcnt lgkmcnt(0)" ::: "memory");
    __builtin_amdgcn_sched_barrier(0);
    __builtin_amdgcn_s_barrier();
  }
#undef STAGE_KV

  const float inv = 1.0f / l_r;
  // lane writes q-row q_glob, d = 16n2 + 4g + r (bf16x4 8B stores)
  __bf16* yrow = Yg + ((size_t)(blockIdx.z * Tlen + q0 + wid * 16 + l16)) * Cdim
               + blockIdx.y * Dh;
  #pragma unroll
  for (int n2 = 0; n2 < 8; ++n2) {
    bf16x4 w;
    #pragma unroll
    for (int r = 0; r < 4; ++r) w[r] = (__bf16)(o[n2][r] * inv);
    *(bf16x4*)&yrow[n2 * 16 + 4 * g] = w;
  }
}

// ---- 3) output GEMM: 256x256, 8 waves, BK=64, counted-vmcnt dbuf -----------
__global__ __launch_bounds__(512, 2) void out_gemm(
    const __bf16* __restrict__ Yb, const __bf16* __restrict__ Wt,
    float* __restrict__ O)
{
  __shared__ struct { __bf16 A[2][256 * 64]; __bf16 B[2][256 * 64]; } sm;

  const int tid = threadIdx.x, lane = tid & 63, wid = tid >> 6;
  const int g = lane >> 4, l16 = lane & 15;
  const int wr = wid >> 2, wc = wid & 3;

  const int bid = blockIdx.x;
  const int xcd = bid & 7, idx = bid >> 3;
  const int stl = idx >> 4, pos = idx & 15;
  const int m0 = (xcd * 4 + (pos >> 2)) * 256;
  const int n0 = (stl * 4 + (pos & 3)) * 256;

  const int srow = tid >> 3;
  const int schk = (tid & 7) ^ (srow & 7);
  const __bf16* gA = Yb + (size_t)(m0 + srow) * Cdim + schk * 8;
  const __bf16* gB = Wt + (size_t)(n0 + srow) * Cdim + schk * 8;
  const int ldst = wid * 512;

  f32x4 acc[8][4] = {};
  const int NT = Cdim / 64;

  #pragma unroll
  for (int r = 0; r < 4; ++r) {
    gl16(gA + (size_t)r * 64 * Cdim, &sm.A[0][r * 4096 + ldst]);
    gl16(gB + (size_t)r * 64 * Cdim, &sm.B[0][r * 4096 + ldst]);
  }
  #pragma unroll
  for (int r = 0; r < 4; ++r) {
    gl16(gA + 64 + (size_t)r * 64 * Cdim, &sm.A[1][r * 4096 + ldst]);
    gl16(gB + 64 + (size_t)r * 64 * Cdim, &sm.B[1][r * 4096 + ldst]);
  }

  for (int t = 0; t < NT; ++t) {
    const int p = t & 1;
    if (t < NT - 1) asm volatile("s_waitcnt vmcnt(8)" ::: "memory");
    else            asm volatile("s_waitcnt vmcnt(0)" ::: "memory");
    __builtin_amdgcn_s_barrier();
    __builtin_amdgcn_sched_barrier(0);

    #pragma unroll
    for (int kk = 0; kk < 2; ++kk) {
      bf16x8 a[8], b[4];
      const int ch = (((kk << 2) | g) ^ (l16 & 7)) * 8;
      #pragma unroll
      for (int f = 0; f < 8; ++f)
        a[f] = *(const bf16x8*)&sm.A[p][(wr * 128 + f * 16 + l16) * 64 + ch];
      #pragma unroll
      for (int n = 0; n < 4; ++n)
        b[n] = *(const bf16x8*)&sm.B[p][(wc * 64 + n * 16 + l16) * 64 + ch];
      #pragma unroll
      for (int f = 0; f < 8; ++f)
        #pragma unroll
        for (int n = 0; n < 4; ++n)
          acc[f][n] = mfma16(a[f], b[n], acc[f][n]);
    }

    __builtin_amdgcn_sched_barrier(0);
    asm volatile("s_waitcnt lgkmcnt(0)" ::: "memory");
    __builtin_amdgcn_s_barrier();

    if (t + 2 < NT) {
      const __bf16* pA = gA + (size_t)(t + 2) * 64;
      const __bf16* pB = gB + (size_t)(t + 2) * 64;
      #pragma unroll
      for (int r = 0; r < 4; ++r) {
        gl16(pA + (size_t)r * 64 * Cdim, &sm.A[p][r * 4096 + ldst]);
        gl16(pB + (size_t)r * 64 * Cdim, &sm.B[p][r * 4096 + ldst]);
      }
    }
  }

  #pragma unroll
  for (int f = 0; f < 8; ++f)
    #pragma unroll
    for (int n = 0; n < 4; ++n)
      #pragma unroll
      for (int r = 0; r < 4; ++r)
        O[(size_t)(m0 + wr * 128 + f * 16 + g * 4 + r) * Cdim
          + (n0 + wc * 64 + n * 16 + l16)] = acc[f][n][r];
}

// ---- launch -----------------------------------------------------------------
extern "C" void kernel_launch(void* const* d_in, const int* in_sizes, int n_in,
                              void* d_out, int out_size, void* d_ws, size_t ws_size,
                              hipStream_t stream) {
  const float* x    = (const float*)d_in[0];
  const float* Wqkv = (const float*)d_in[1];
  const float* Wout = (const float*)d_in[2];
  float* out = (float*)d_out;

  float*  cosT   = (float*)d_ws;
  float*  sinT   = cosT + Tlen * 64;
  __bf16* Xb     = (__bf16*)(sinT + Tlen * 64);            // 32MB (reused as Y)
  __bf16* Wqkv_t = Xb + (size_t)Mrows * Cdim;              // 24MB [6144][2048]
  __bf16* Wout_t = Wqkv_t + (size_t)N_QKV * Cdim;          // 8MB  [2048][2048]
  __bf16* Qb     = Wout_t + (size_t)Cdim * Cdim;           // 32MB [B][H][T][D]
  __bf16* Kb     = Qb + (size_t)Bsz * Hn * Tlen * Dh;      // 32MB [B][H][T][D]
  __bf16* Vb     = Kb + (size_t)Bsz * Hn * Tlen * Dh;      // 32MB [B][H][D][T]
  __bf16* Yb     = Xb;

  rope_table_k<<<dim3(512), dim3(256), 0, stream>>>(cosT, sinT);
  f32_to_bf16_k<<<dim3(Mrows * Cdim / (256 * 8)), dim3(256), 0, stream>>>(x, Xb);
  transpose_to_bf16_k<<<dim3(N_QKV / 32, Cdim / 32), dim3(256), 0, stream>>>(
      Wqkv, Wqkv_t, Cdim, N_QKV);
  transpose_to_bf16_k<<<dim3(Cdim / 32, Cdim / 32), dim3(256), 0, stream>>>(
      Wout, Wout_t, Cdim, Cdim);
  qkv_gemm<<<dim3(768), dim3(512), 0, stream>>>(
      Xb, Wqkv_t, Qb, Kb, Vb, cosT, sinT);
  attn_fwd<<<dim3(Tlen / 64, Hn, Bsz), dim3(256), 0, stream>>>(Qb, Kb, Vb, Yb);
  out_gemm<<<dim3(256), dim3(512), 0, stream>>>(Yb, Wout_t, out);
}